// Round 1
// baseline (660.217 us; speedup 1.0000x reference)
//
#include <hip/hip_runtime.h>
#include <cstdint>
#include <cstddef>

#define B_ 4
#define C_ 512
#define T_ 2048
#define S_ 2048
#define EPSF 1e-5f

typedef __bf16 bf16;
typedef __attribute__((ext_vector_type(8))) __bf16 bf16x8;
typedef __attribute__((ext_vector_type(4))) float f32x4;

__device__ __forceinline__ bf16 f2b(float f){ return (bf16)f; }
__device__ __forceinline__ float b2f(bf16 h){ return (float)h; }

__device__ __forceinline__ void gl_lds16(const void* g, void* l){
  __builtin_amdgcn_global_load_lds((__attribute__((address_space(1))) void*)(g),
                                   (__attribute__((address_space(3))) void*)(l), 16, 0, 0);
}

__device__ __forceinline__ float wave_sum(float v){
#pragma unroll
  for (int o = 32; o; o >>= 1) v += __shfl_xor(v, o, 64);
  return v;
}
__device__ __forceinline__ float wave_max(float v){
#pragma unroll
  for (int o = 32; o; o >>= 1) v = fmaxf(v, __shfl_xor(v, o, 64));
  return v;
}

// ---------------------------------------------------------------------------
// NT GEMM: C[m,n] = sum_k A[m,k]*B[n,k], both operands k-contiguous (bf16),
// fp32 MFMA accum. 128x128 tile, BK=64, 256 threads (2x2 waves of 64x64).
// EPI 0: bf16 store of (acc*scale + cbias[n]) ; 1: f32 store ;
// EPI 2: f32 store of relu(acc*rs[m] + rsh[m])   (BN+ReLU)
// ---------------------------------------------------------------------------
template<int EPI>
__global__ void __launch_bounds__(256) gemm_nt(
    const bf16* __restrict__ A, const bf16* __restrict__ Bm, void* __restrict__ Cout,
    int K, int lda, int ldb, int ldc,
    long long sA, long long sB, long long sC, long long sCb,
    float scale, const float* __restrict__ rs, const float* __restrict__ rsh,
    const float* __restrict__ cbias)
{
  __shared__ alignas(16) bf16 lA[128*64];
  __shared__ alignas(16) bf16 lB[128*64];
  const int tid = threadIdx.x;
  const int z = blockIdx.z;
  const bf16* Ab = A + z*sA;
  const bf16* Bb = Bm + z*sB;
  const int m0 = blockIdx.y*128, n0 = blockIdx.x*128;
  const int lane = tid & 63, wvi = tid >> 6;
  const int wm = wvi >> 1, wn = wvi & 1;

  f32x4 acc[4][4] = {};

  // loader: thread tid stages one 16B chunk per iter; XOR-swizzle the k-chunk
  // position by (row&7) so MFMA-phase ds_read_b128 spreads across all banks.
  const int lrow = tid >> 3;
  const int lcol = ((tid ^ lrow) & 7) * 8;
  const bf16* pa = Ab + (long long)(m0 + lrow)*lda + lcol;
  const bf16* pb = Bb + (long long)(n0 + lrow)*ldb + lcol;
  char* sa = (char*)lA + tid*16;
  char* sb = (char*)lB + tid*16;

  for (int k0 = 0; k0 < K; k0 += 64) {
#pragma unroll
    for (int it = 0; it < 4; ++it) {
      gl_lds16(pa + (long long)it*32*lda + k0, sa + it*4096);
      gl_lds16(pb + (long long)it*32*ldb + k0, sb + it*4096);
    }
    __syncthreads();
#pragma unroll
    for (int ks = 0; ks < 2; ++ks) {
      const int kq = ks*4 + (lane >> 4);
      bf16x8 af[4], bfr[4];
#pragma unroll
      for (int mt = 0; mt < 4; ++mt) {
        int r = wm*64 + mt*16 + (lane & 15);
        af[mt] = *(const bf16x8*)&lA[r*64 + ((kq ^ (r & 7))*8)];
      }
#pragma unroll
      for (int nt = 0; nt < 4; ++nt) {
        int r = wn*64 + nt*16 + (lane & 15);
        bfr[nt] = *(const bf16x8*)&lB[r*64 + ((kq ^ (r & 7))*8)];
      }
#pragma unroll
      for (int mt = 0; mt < 4; ++mt)
#pragma unroll
        for (int nt = 0; nt < 4; ++nt)
          acc[mt][nt] = __builtin_amdgcn_mfma_f32_16x16x32_bf16(af[mt], bfr[nt], acc[mt][nt], 0, 0, 0);
    }
    __syncthreads();
  }

  const int cr = (lane >> 4)*4, cc = lane & 15;
#pragma unroll
  for (int mt = 0; mt < 4; ++mt) {
#pragma unroll
    for (int i = 0; i < 4; ++i) {
      const int mm = m0 + wm*64 + mt*16 + cr + i;
#pragma unroll
      for (int nt = 0; nt < 4; ++nt) {
        const int nn = n0 + wn*64 + nt*16 + cc;
        float v = acc[mt][nt][i];
        const long long co = sC*z + (long long)mm*ldc + nn;
        if (EPI == 0) {
          v *= scale;
          if (cbias) v += cbias[sCb*z + nn];
          ((bf16*)Cout)[co] = f2b(v);
        } else if (EPI == 1) {
          ((float*)Cout)[co] = v;
        } else {
          ((float*)Cout)[co] = fmaxf(v*rs[mm] + rsh[mm], 0.f);
        }
      }
    }
  }
}

// ---- per-row (contiguous, len 2048) mean/std, ddof=1 -----------------------
__global__ void __launch_bounds__(256) row_stats_k(const float* __restrict__ X,
    float* __restrict__ Mo, float* __restrict__ So)
{
  __shared__ float r1[4], r2[4];
  const long long row = blockIdx.x;
  const float* x = X + row*T_;
  float s1 = 0.f, s2 = 0.f;
  for (int i = threadIdx.x; i < T_; i += 256){ float v = x[i]; s1 += v; s2 += v*v; }
  s1 = wave_sum(s1); s2 = wave_sum(s2);
  const int lane = threadIdx.x & 63, w = threadIdx.x >> 6;
  if (!lane){ r1[w] = s1; r2[w] = s2; }
  __syncthreads();
  if (threadIdx.x == 0){
    s1 = r1[0]+r1[1]+r1[2]+r1[3];
    s2 = r2[0]+r2[1]+r2[2]+r2[3];
    float m = s1 * (1.f/T_);
    float var = (s2 - s1*m) * (1.f/(T_-1));
    Mo[row] = m; So[row] = sqrtf(fmaxf(var, 0.f));
  }
}

// ---- per-(b,t) mean/std over channels (strided), ddof=1 --------------------
__global__ void __launch_bounds__(256) col_stats_k(const float* __restrict__ X,
    float* __restrict__ Mo, float* __restrict__ So)
{
  __shared__ float r1[4][64], r2[4][64];
  const int b = blockIdx.y, t0 = blockIdx.x*64;
  const int tl = threadIdx.x & 63, cg = threadIdx.x >> 6;
  float s1 = 0.f, s2 = 0.f;
  for (int c = cg; c < C_; c += 4) {
    float v = X[((long long)b*C_ + c)*T_ + t0 + tl];
    s1 += v; s2 += v*v;
  }
  r1[cg][tl] = s1; r2[cg][tl] = s2;
  __syncthreads();
  if (cg == 0) {
    s1 = r1[0][tl]+r1[1][tl]+r1[2][tl]+r1[3][tl];
    s2 = r2[0][tl]+r2[1][tl]+r2[2][tl]+r2[3][tl];
    float m = s1 * (1.f/C_);
    float var = (s2 - s1*m) * (1.f/(C_-1));
    Mo[b*T_ + t0 + tl] = m;
    So[b*T_ + t0 + tl] = sqrtf(fmaxf(var, 0.f));
  }
}

// ---- transpose [C,T]->[T,C] + write tinorm & inorm normalized bf16 ---------
__global__ void __launch_bounds__(256) transform_src_k(const float* __restrict__ src,
    const float* __restrict__ tnm, const float* __restrict__ tns,
    const float* __restrict__ inm, const float* __restrict__ ins,
    bf16* __restrict__ NSt, bf16* __restrict__ NSc)
{
  __shared__ float tile[32][33];
  const int b = blockIdx.z, t0 = blockIdx.x*32, c0 = blockIdx.y*32;
  const int tx = threadIdx.x, ty = threadIdx.y;
#pragma unroll
  for (int r = 0; r < 4; ++r) {
    int ci = ty + r*8;
    tile[ci][tx] = src[((long long)b*C_ + c0 + ci)*T_ + t0 + tx];
  }
  __syncthreads();
#pragma unroll
  for (int r = 0; r < 4; ++r) {
    int tj = ty + r*8, ci = tx;
    float v = tile[ci][tj];
    int gt = t0 + tj, gc = c0 + ci;
    float a = (v - tnm[b*T_ + gt]) / (tns[b*T_ + gt] + EPSF);
    float d = (v - inm[b*C_ + gc]) / (ins[b*C_ + gc] + EPSF);
    long long o = ((long long)b*T_ + gt)*C_ + gc;
    NSt[o] = f2b(a);
    NSc[o] = f2b(d);
  }
}

__global__ void __launch_bounds__(256) transform_trg_k(const float* __restrict__ trg,
    const float* __restrict__ tnm, const float* __restrict__ tns,
    const float* __restrict__ inm, const float* __restrict__ ins,
    bf16* __restrict__ NTt, bf16* __restrict__ NTc, bf16* __restrict__ TTr)
{
  __shared__ float tile[32][33];
  const int b = blockIdx.z, t0 = blockIdx.x*32, c0 = blockIdx.y*32;
  const int tx = threadIdx.x, ty = threadIdx.y;
#pragma unroll
  for (int r = 0; r < 4; ++r) {
    int ci = ty + r*8;
    tile[ci][tx] = trg[((long long)b*C_ + c0 + ci)*T_ + t0 + tx];
  }
  __syncthreads();
#pragma unroll
  for (int r = 0; r < 4; ++r) {
    int tj = ty + r*8, ci = tx;
    float v = tile[ci][tj];
    int gt = t0 + tj, gc = c0 + ci;
    float a = (v - tnm[b*T_ + gt]) / (tns[b*T_ + gt] + EPSF);
    float d = (v - inm[b*C_ + gc]) / (ins[b*C_ + gc] + EPSF);
    long long o = ((long long)b*T_ + gt)*C_ + gc;
    NTt[o] = f2b(a);
    NTc[o] = f2b(d);
    TTr[o] = f2b(v);
  }
}

// ---- row softmax over 2048, fp32 in, OT out --------------------------------
template<typename OT>
__global__ void __launch_bounds__(256) softmax_row_k(const float* __restrict__ X, OT* __restrict__ O)
{
  __shared__ float red[4];
  const long long row = blockIdx.x;
  const float* x = X + row*T_ + threadIdx.x*8;
  float v[8];
  f32x4 a0 = *(const f32x4*)x;
  f32x4 a1 = *(const f32x4*)(x + 4);
#pragma unroll
  for (int j = 0; j < 4; ++j){ v[j] = a0[j]; v[4+j] = a1[j]; }
  float m = -3.4e38f;
#pragma unroll
  for (int j = 0; j < 8; ++j) m = fmaxf(m, v[j]);
  m = wave_max(m);
  const int lane = threadIdx.x & 63, w = threadIdx.x >> 6;
  if (!lane) red[w] = m;
  __syncthreads();
  m = fmaxf(fmaxf(red[0], red[1]), fmaxf(red[2], red[3]));
  __syncthreads();
  float s = 0.f;
#pragma unroll
  for (int j = 0; j < 8; ++j){ v[j] = __expf(v[j] - m); s += v[j]; }
  s = wave_sum(s);
  if (!lane) red[w] = s;
  __syncthreads();
  s = red[0]+red[1]+red[2]+red[3];
  const float inv = 1.f/s;
  OT* o = O + row*T_ + threadIdx.x*8;
#pragma unroll
  for (int j = 0; j < 8; ++j) o[j] = (OT)(v[j]*inv);
}

// ---- column sums of P over s (chunked, atomic) -----------------------------
__global__ void __launch_bounds__(256) colsum_k(const bf16* __restrict__ P, float* __restrict__ cs)
{
  const int t = blockIdx.x*256 + threadIdx.x;
  const int b = blockIdx.z;
  const long long s0 = (long long)blockIdx.y*256;
  const bf16* p = P + ((long long)b*S_ + s0)*T_ + t;
  float a = 0.f;
  for (int s = 0; s < 256; ++s) a += b2f(p[(long long)s*T_]);
  atomicAdd(&cs[b*T_ + t], a);
}

// ---- sum_s mean and sum_s mean^2 (chunked, atomic) -------------------------
__global__ void __launch_bounds__(256) mean_reduce_k(const float* __restrict__ mean,
    float* __restrict__ ms, float* __restrict__ m2s)
{
  const int c = blockIdx.x*256 + threadIdx.x;
  const int b = blockIdx.z;
  const long long s0 = (long long)blockIdx.y*128;
  const float* p = mean + ((long long)b*S_ + s0)*C_ + c;
  float s1 = 0.f, s2 = 0.f;
  for (int s = 0; s < 128; ++s){ float v = p[(long long)s*C_]; s1 += v; s2 += v*v; }
  atomicAdd(&ms[b*C_ + c], s1);
  atomicAdd(&m2s[b*C_ + c], s2);
}

// ---- vv-GEMV + finalize mean_c / std_c -------------------------------------
__global__ void __launch_bounds__(256) vv_fin_k(const float* __restrict__ cs,
    const bf16* __restrict__ VT, const float* __restrict__ msum,
    const float* __restrict__ m2sum, float* __restrict__ meanc, float* __restrict__ stdc)
{
  __shared__ float r1[4];
  const int c = blockIdx.x, b = blockIdx.y;
  const bf16* vr = VT + ((long long)b*C_ + c)*T_;
  const float* w = cs + b*T_;
  float a = 0.f;
  for (int t = threadIdx.x; t < T_; t += 256){ float v = b2f(vr[t]); a += w[t]*v*v; }
  a = wave_sum(a);
  const int lane = threadIdx.x & 63, wq = threadIdx.x >> 6;
  if (!lane) r1[wq] = a;
  __syncthreads();
  if (threadIdx.x == 0){
    a = r1[0]+r1[1]+r1[2]+r1[3];
    const int idx = b*C_ + c;
    meanc[idx] = msum[idx] * (1.f/S_);
    float var = (a - m2sum[idx]) * (1.f/S_);
    stdc[idx] = sqrtf(fmaxf(var, 0.f));
  }
}

// ---- fold adaptive-norm epilogue + concat into conv1 weights ---------------
__global__ void __launch_bounds__(256) weff_k(const float* __restrict__ w1,
    const float* __restrict__ b1, const float* __restrict__ sdt, const float* __restrict__ sdc,
    const float* __restrict__ mct, const float* __restrict__ mcc,
    bf16* __restrict__ Weff, float* __restrict__ beff)
{
  __shared__ float r1[4];
  const int o = blockIdx.x, b = blockIdx.y;
  float accb = 0.f;
  for (int c = threadIdx.x; c < C_; c += 256) {
    float wa = w1[o*2*C_ + c], wb = w1[o*2*C_ + C_ + c];
    Weff[((long long)(b*C_ + o))*C_ + c] = f2b(wa*sdt[b*C_+c] + wb*sdc[b*C_+c]);
    accb += wa*mct[b*C_+c] + wb*mcc[b*C_+c];
  }
  accb = wave_sum(accb);
  const int lane = threadIdx.x & 63, w = threadIdx.x >> 6;
  if (!lane) r1[w] = accb;
  __syncthreads();
  if (threadIdx.x == 0) beff[b*C_ + o] = b1[o] + r1[0]+r1[1]+r1[2]+r1[3];
}

// ---- conv2 weight reorder (k = dt*C + c) + BN scale/shift ------------------
__global__ void __launch_bounds__(256) w2r_k(const float* __restrict__ w2,
    const float* __restrict__ g, const float* __restrict__ be,
    const float* __restrict__ mu, const float* __restrict__ va,
    bf16* __restrict__ W2r, float* __restrict__ bnsc, float* __restrict__ bnsh)
{
  const int o = blockIdx.x;
  for (int c = threadIdx.x; c < C_; c += 256)
#pragma unroll
    for (int dt = 0; dt < 3; ++dt)
      W2r[(long long)o*3*C_ + dt*C_ + c] = f2b(w2[((long long)o*C_ + c)*3 + dt]);
  if (threadIdx.x == 0) {
    float s = g[o] * rsqrtf(va[o] + EPSF);
    bnsc[o] = s;
    bnsh[o] = be[o] - mu[o]*s;
  }
}

// ---- cast the 6 projection weight matrices to bf16 -------------------------
__global__ void __launch_bounds__(256) cast6_k(const float* __restrict__ a0,
    const float* __restrict__ a1, const float* __restrict__ a2, const float* __restrict__ a3,
    const float* __restrict__ a4, const float* __restrict__ a5, bf16* __restrict__ o)
{
  const int i = blockIdx.x*256 + threadIdx.x;   // 6*262144 total
  const float* srcs[6] = {a0,a1,a2,a3,a4,a5};
  o[i] = f2b(srcs[i >> 18][i & 262143]);
}

// ---- zero pad rows of x1p --------------------------------------------------
__global__ void __launch_bounds__(256) zero_pad_k(bf16* __restrict__ x1p)
{
  const int i = blockIdx.x*256 + threadIdx.x;   // 4096
  const int b = i >> 10, rem = i & 1023;
  const long long row = (rem >> 9) ? (T_+1) : 0;
  const int c = rem & (C_-1);
  x1p[((long long)b*(T_+2) + row)*C_ + c] = f2b(0.f);
}

__global__ void __launch_bounds__(256) zero_f32_k(float* __restrict__ p)
{
  p[blockIdx.x*256 + threadIdx.x] = 0.f;
}

// ---- SAP: logits -----------------------------------------------------------
__global__ void __launch_bounds__(256) sap_logit_k(const float* __restrict__ x,
    const float* __restrict__ w, const float* __restrict__ bias, float* __restrict__ out)
{
  const int n = blockIdx.x*4 + (threadIdx.x >> 6);
  const int b = blockIdx.y;
  const int lane = threadIdx.x & 63;
  const float* p = x + ((long long)b*S_ + n)*C_;
  float a = 0.f;
  for (int c = lane; c < C_; c += 64) a += p[c]*w[c];
  a = wave_sum(a);
  if (!lane) out[b*S_ + n] = a + bias[0];
}

// ---- SAP: weighted sum over n (chunked, atomic) ----------------------------
__global__ void __launch_bounds__(256) sap_wsum_k(const float* __restrict__ x,
    const float* __restrict__ a, float* __restrict__ out)
{
  const int c = blockIdx.x*256 + threadIdx.x;
  const int b = blockIdx.z;
  const long long n0 = (long long)blockIdx.y*256;
  const float* p = x + ((long long)b*S_ + n0)*C_ + c;
  const float* aw = a + b*S_ + n0;
  float acc = 0.f;
  for (int n = 0; n < 256; ++n) acc += p[(long long)n*C_] * aw[n];
  atomicAdd(&out[b*C_ + c], acc);
}

// ---- final: inorm(y)*sap_std + sap_mean ------------------------------------
__global__ void __launch_bounds__(256) final_k(const float* __restrict__ y,
    const float* __restrict__ ym, const float* __restrict__ ys,
    const float* __restrict__ sm, const float* __restrict__ ss,
    float* __restrict__ out)
{
  const long long i = (long long)(blockIdx.x*256 + threadIdx.x) * 4;
  const long long r = i >> 11;
  const float m = ym[r], inv = 1.f/(ys[r] + EPSF);
  const float sd = ss[r], mn = sm[r];
  const f32x4 v = *(const f32x4*)(y + i);
  f32x4 o;
#pragma unroll
  for (int j = 0; j < 4; ++j) o[j] = (v[j] - m)*inv*sd + mn;
  *(f32x4*)(out + i) = o;
}

// ---------------------------------------------------------------------------
extern "C" void kernel_launch(void* const* d_in, const int* in_sizes, int n_in,
                              void* d_out, int out_size, void* d_ws, size_t ws_size,
                              hipStream_t stream)
{
  (void)in_sizes; (void)n_in; (void)out_size; (void)ws_size;
  const float* src    = (const float*)d_in[0];
  const float* trg    = (const float*)d_in[1];
  const float* means  = (const float*)d_in[2];
  const float* stds   = (const float*)d_in[3];
  const float* conv1w = (const float*)d_in[10];
  const float* conv1b = (const float*)d_in[11];
  const float* conv2w = (const float*)d_in[12];
  const float* bn_g   = (const float*)d_in[13];
  const float* bn_b   = (const float*)d_in[14];
  const float* bn_m   = (const float*)d_in[15];
  const float* bn_v   = (const float*)d_in[16];
  const float* msap_w = (const float*)d_in[17];
  const float* msap_b = (const float*)d_in[18];
  const float* ssap_w = (const float*)d_in[19];
  const float* ssap_b = (const float*)d_in[20];

  const long long BTC = (long long)B_*T_*C_;   // 4194304 elems
  const long long BSS = (long long)B_*S_*T_;   // 16777216 elems

  char* p = (char*)d_ws;
  auto take = [&](size_t n)->char*{ char* r = p; p += (n + 255) & ~(size_t)255; return r; };

  // P [B,S,T] bf16 aliases {NSt,NTt,Qb,Kb} (all dead when P is alive)
  bf16* NSt = (bf16*)take(BTC*2);
  bf16* NTt = (bf16*)take(BTC*2);
  bf16* Qb  = (bf16*)take(BTC*2);
  bf16* Kb  = (bf16*)take(BTC*2);
  bf16* Pb  = NSt;
  bf16* NSc = (bf16*)take(BTC*2);
  bf16* NTc = (bf16*)take(BTC*2);
  bf16* TTr = (bf16*)take(BTC*2);
  bf16* VTb = (bf16*)take(BTC*2);
  bf16* WQb = (bf16*)take((size_t)6*C_*C_*2);
  bf16* Weff= (bf16*)take((size_t)B_*C_*C_*2);
  bf16* W2r = (bf16*)take((size_t)C_*3*C_*2);
  bf16* x1p = (bf16*)take((size_t)B_*(T_+2)*C_*2);
  float* Slog    = (float*)take(BSS*4);
  float* meanbuf = (float*)take((size_t)B_*S_*C_*4);
  float* y = meanbuf;                              // meanbuf dead before conv2
  float* colsum  = (float*)take(B_*T_*4);          // keep these 3 contiguous:
  float* meansum = (float*)take(B_*C_*4);          //  one zero kernel covers
  float* mean2sum= (float*)take(B_*C_*4);          //  12288 floats
  float* tnm_s = (float*)take(B_*T_*4);
  float* tns_s = (float*)take(B_*T_*4);
  float* tnm_t = (float*)take(B_*T_*4);
  float* tns_t = (float*)take(B_*T_*4);
  float* inm_s = (float*)take(B_*C_*4);
  float* ins_s = (float*)take(B_*C_*4);
  float* inm_t = (float*)take(B_*C_*4);
  float* ins_t = (float*)take(B_*C_*4);
  float* meanc_t=(float*)take(B_*C_*4);
  float* stdc_t =(float*)take(B_*C_*4);
  float* meanc_c=(float*)take(B_*C_*4);
  float* stdc_c =(float*)take(B_*C_*4);
  float* beff  = (float*)take(B_*C_*4);
  float* bnsc  = (float*)take(C_*4);
  float* bnsh  = (float*)take(C_*4);
  float* ym    = (float*)take(B_*C_*4);
  float* ys    = (float*)take(B_*C_*4);
  float* sapl  = (float*)take(B_*S_*4);
  float* sapa  = (float*)take(B_*S_*4);
  float* sapm  = (float*)take(B_*C_*4);            // sapm+saps contiguous
  float* saps  = (float*)take(B_*C_*4);

  const float qsc = 0.044194173824159216f;         // 1/sqrt(512) (temp)
  dim3 blk(256);

  cast6_k<<<6144, blk, 0, stream>>>((const float*)d_in[4], (const float*)d_in[5],
      (const float*)d_in[6], (const float*)d_in[7], (const float*)d_in[8],
      (const float*)d_in[9], WQb);
  w2r_k<<<C_, blk, 0, stream>>>(conv2w, bn_g, bn_b, bn_m, bn_v, W2r, bnsc, bnsh);
  row_stats_k<<<B_*C_, blk, 0, stream>>>(src, inm_s, ins_s);
  row_stats_k<<<B_*C_, blk, 0, stream>>>(trg, inm_t, ins_t);
  col_stats_k<<<dim3(T_/64, B_), blk, 0, stream>>>(src, tnm_s, tns_s);
  col_stats_k<<<dim3(T_/64, B_), blk, 0, stream>>>(trg, tnm_t, tns_t);
  transform_src_k<<<dim3(T_/32, C_/32, B_), dim3(32,8), 0, stream>>>(src, tnm_s, tns_s, inm_s, ins_s, NSt, NSc);
  transform_trg_k<<<dim3(T_/32, C_/32, B_), dim3(32,8), 0, stream>>>(trg, tnm_t, tns_t, inm_t, ins_t, NTt, NTc, TTr);
  zero_pad_k<<<16, blk, 0, stream>>>(x1p);

  for (int ph = 0; ph < 2; ++ph) {
    const bf16* NS = ph ? NSc : NSt;
    const bf16* NT = ph ? NTc : NTt;
    const bf16* wq = WQb + (size_t)(ph ? 3 : 0)*C_*C_;
    const bf16* wk = WQb + (size_t)(ph ? 4 : 1)*C_*C_;
    const bf16* wvp= WQb + (size_t)(ph ? 5 : 2)*C_*C_;
    float* mc = ph ? meanc_c : meanc_t;
    float* sc = ph ? stdc_c  : stdc_t;

    // Q = NS @ wq^T (scaled 1/temp), K = NT @ wk^T   [B*T, C]
    gemm_nt<0><<<dim3(C_/128, (B_*T_)/128, 1), blk, 0, stream>>>(NS, wq, Qb,
        C_, C_, C_, C_, 0, 0, 0, 0, qsc, nullptr, nullptr, nullptr);
    gemm_nt<0><<<dim3(C_/128, (B_*T_)/128, 1), blk, 0, stream>>>(NT, wk, Kb,
        C_, C_, C_, C_, 0, 0, 0, 0, 1.f, nullptr, nullptr, nullptr);
    // V^T[b] = wv @ TTr[b]^T  -> [C, T] (k-contig for PV's B operand)
    gemm_nt<0><<<dim3(T_/128, C_/128, B_), blk, 0, stream>>>(wvp, TTr, VTb,
        C_, C_, C_, T_, 0, (long long)T_*C_, (long long)C_*T_, 0, 1.f, nullptr, nullptr, nullptr);
    // S = Q @ K^T (fp32 logits)
    gemm_nt<1><<<dim3(T_/128, T_/128, B_), blk, 0, stream>>>(Qb, Kb, Slog,
        C_, C_, C_, T_, (long long)T_*C_, (long long)T_*C_, (long long)T_*T_, 0,
        1.f, nullptr, nullptr, nullptr);
    softmax_row_k<bf16><<<B_*S_, blk, 0, stream>>>(Slog, Pb);
    zero_f32_k<<<48, blk, 0, stream>>>(colsum);    // colsum+meansum+mean2sum
    colsum_k<<<dim3(T_/256, S_/256, B_), blk, 0, stream>>>(Pb, colsum);
    // mean = P @ V
    gemm_nt<1><<<dim3(C_/128, S_/128, B_), blk, 0, stream>>>(Pb, VTb, meanbuf,
        T_, T_, T_, C_, (long long)S_*T_, (long long)C_*T_, (long long)S_*C_, 0,
        1.f, nullptr, nullptr, nullptr);
    mean_reduce_k<<<dim3(C_/256, S_/128, B_), blk, 0, stream>>>(meanbuf, meansum, mean2sum);
    vv_fin_k<<<dim3(C_, B_), blk, 0, stream>>>(colsum, VTb, meansum, mean2sum, mc, sc);
  }

  weff_k<<<dim3(C_, B_), blk, 0, stream>>>(conv1w, conv1b, stdc_t, stdc_c, meanc_t, meanc_c, Weff, beff);
  // conv1 (folded): x1[b,t,o] = sum_c NSc[b,t,c]*Weff[b,o,c] + beff[b,o]
  gemm_nt<0><<<dim3(C_/128, T_/128, B_), blk, 0, stream>>>(NSc, Weff, x1p + C_,
      C_, C_, C_, C_, (long long)T_*C_, (long long)C_*C_, (long long)(T_+2)*C_, C_,
      1.f, nullptr, nullptr, beff);
  // conv2 (k=3) as overlapping-row NT GEMM, K=3C, ldb=C; BN+ReLU epilogue
  gemm_nt<2><<<dim3(T_/128, C_/128, B_), blk, 0, stream>>>(W2r, x1p, y,
      3*C_, 3*C_, C_, T_, 0, (long long)(T_+2)*C_, (long long)C_*T_, 0,
      1.f, bnsc, bnsh, nullptr);
  row_stats_k<<<B_*C_, blk, 0, stream>>>(y, ym, ys);

  sap_logit_k<<<dim3(S_/4, B_), blk, 0, stream>>>(means, msap_w, msap_b, sapl);
  softmax_row_k<float><<<B_, blk, 0, stream>>>(sapl, sapa);
  zero_f32_k<<<16, blk, 0, stream>>>(sapm);        // sapm+saps
  sap_wsum_k<<<dim3(C_/256, S_/256, B_), blk, 0, stream>>>(means, sapa, sapm);
  sap_logit_k<<<dim3(S_/4, B_), blk, 0, stream>>>(stds, ssap_w, ssap_b, sapl);
  softmax_row_k<float><<<B_, blk, 0, stream>>>(sapl, sapa);
  sap_wsum_k<<<dim3(C_/256, S_/256, B_), blk, 0, stream>>>(stds, sapa, saps);

  final_k<<<4096, blk, 0, stream>>>(y, ym, ys, sapm, saps, (float*)d_out);
}

// Round 2
// 564.812 us; speedup vs baseline: 1.1689x; 1.1689x over previous
//
#include <hip/hip_runtime.h>
#include <cstdint>
#include <cstddef>

#define B_ 4
#define C_ 512
#define T_ 2048
#define S_ 2048
#define EPSF 1e-5f

typedef __bf16 bf16;
typedef __attribute__((ext_vector_type(8))) __bf16 bf16x8;
typedef __attribute__((ext_vector_type(4))) float f32x4;

__device__ __forceinline__ bf16 f2b(float f){ return (bf16)f; }
__device__ __forceinline__ float b2f(bf16 h){ return (float)h; }

__device__ __forceinline__ void gl_lds16(const void* g, void* l){
  __builtin_amdgcn_global_load_lds((__attribute__((address_space(1))) void*)(g),
                                   (__attribute__((address_space(3))) void*)(l), 16, 0, 0);
}

__device__ __forceinline__ float wave_sum(float v){
#pragma unroll
  for (int o = 32; o; o >>= 1) v += __shfl_xor(v, o, 64);
  return v;
}
__device__ __forceinline__ float wave_max(float v){
#pragma unroll
  for (int o = 32; o; o >>= 1) v = fmaxf(v, __shfl_xor(v, o, 64));
  return v;
}

// ---------------------------------------------------------------------------
// NT GEMM: C[m,n] = sum_k A[m,k]*B[n,k], both operands k-contiguous (bf16),
// fp32 MFMA accum. Tile 128 x (TNW*32), BK=64, 256 threads (2x2 waves).
// z-batched: A offset (z/zdivA)*sA, B offset (z%zmodB)*sB, C offset z*sC.
// EPI 0: bf16 store (acc*scale + cbias[n]) ; 1: f32 store ;
// EPI 2: f32 store relu(acc*rs[m]+rsh[m]) (BN+ReLU) ;
// EPI 3: no store — atomicAdd per-column sum/sum^2 over m into osum/osum2.
// ---------------------------------------------------------------------------
template<int EPI, int TNW>
__global__ void __launch_bounds__(256) gemm_nt(
    const bf16* __restrict__ A, const bf16* __restrict__ Bm, void* __restrict__ Cout,
    int K, int lda, int ldb, int ldc,
    long long sA, long long sB, long long sC, long long sCb,
    int zdivA, int zmodB, float scale,
    const float* __restrict__ rs, const float* __restrict__ rsh,
    const float* __restrict__ cbias,
    float* __restrict__ osum, float* __restrict__ osum2)
{
  constexpr int TN = TNW*32;
  __shared__ alignas(16) bf16 lA[128*64];
  __shared__ alignas(16) bf16 lB[TN*64];
  const int tid = threadIdx.x;
  const int z = blockIdx.z;
  const bf16* Ab = A + (long long)(z / zdivA) * sA;
  const bf16* Bb = Bm + (long long)(z % zmodB) * sB;
  const int m0 = blockIdx.y*128, n0 = blockIdx.x*TN;
  const int lane = tid & 63, wvi = tid >> 6;
  const int wm = wvi >> 1, wn = wvi & 1;

  f32x4 acc[4][TNW] = {};

  // loader: thread stages one 16B chunk/iter; XOR-swizzle k-chunk by (row&7)
  const int lrow = tid >> 3;
  const int lcol = ((tid ^ lrow) & 7) * 8;
  const bf16* pa = Ab + (long long)(m0 + lrow)*lda + lcol;
  const bf16* pb = Bb + (long long)(n0 + lrow)*ldb + lcol;
  char* sa = (char*)lA + tid*16;
  char* sb = (char*)lB + tid*16;

  for (int k0 = 0; k0 < K; k0 += 64) {
#pragma unroll
    for (int it = 0; it < 4; ++it)
      gl_lds16(pa + (long long)it*32*lda + k0, sa + it*4096);
#pragma unroll
    for (int it = 0; it < TNW; ++it)
      gl_lds16(pb + (long long)it*32*ldb + k0, sb + it*4096);
    __syncthreads();
#pragma unroll
    for (int ks = 0; ks < 2; ++ks) {
      const int kq = ks*4 + (lane >> 4);
      bf16x8 af[4], bfr[TNW];
#pragma unroll
      for (int mt = 0; mt < 4; ++mt) {
        int r = wm*64 + mt*16 + (lane & 15);
        af[mt] = *(const bf16x8*)&lA[r*64 + ((kq ^ (r & 7))*8)];
      }
#pragma unroll
      for (int nt = 0; nt < TNW; ++nt) {
        int r = wn*(TNW*16) + nt*16 + (lane & 15);
        bfr[nt] = *(const bf16x8*)&lB[r*64 + ((kq ^ (r & 7))*8)];
      }
#pragma unroll
      for (int mt = 0; mt < 4; ++mt)
#pragma unroll
        for (int nt = 0; nt < TNW; ++nt)
          acc[mt][nt] = __builtin_amdgcn_mfma_f32_16x16x32_bf16(af[mt], bfr[nt], acc[mt][nt], 0, 0, 0);
    }
    __syncthreads();
  }

  if (EPI == 3) {
    // per-column (n) sum and sum^2 over the block's 128 m-rows -> atomicAdd
    __shared__ float red1[4][TNW][16], red2[4][TNW][16];
    float s1[TNW], s2[TNW];
#pragma unroll
    for (int nt = 0; nt < TNW; ++nt) {
      s1[nt] = 0.f; s2[nt] = 0.f;
#pragma unroll
      for (int mt = 0; mt < 4; ++mt)
#pragma unroll
        for (int i = 0; i < 4; ++i) {
          float v = acc[mt][nt][i];
          s1[nt] += v; s2[nt] += v*v;
        }
      s1[nt] += __shfl_xor(s1[nt], 16, 64);
      s1[nt] += __shfl_xor(s1[nt], 32, 64);
      s2[nt] += __shfl_xor(s2[nt], 16, 64);
      s2[nt] += __shfl_xor(s2[nt], 32, 64);
    }
    if (lane < 16) {
#pragma unroll
      for (int nt = 0; nt < TNW; ++nt) {
        red1[wvi][nt][lane] = s1[nt];
        red2[wvi][nt][lane] = s2[nt];
      }
    }
    __syncthreads();
    if (tid < 2*TN) {
      const int which = tid >= TN;
      const int col = tid - which*TN;
      const int wn2 = col / (TNW*16), rem = col % (TNW*16);
      const float* rr = which ? &red2[0][0][0] : &red1[0][0][0];
      float v = rr[wn2*(TNW*16) + rem] + rr[(2+wn2)*(TNW*16) + rem];
      float* dst = which ? osum2 : osum;
      atomicAdd(&dst[sCb*z + n0 + col], v);
    }
    return;
  }

  const int cr = (lane >> 4)*4, cc = lane & 15;
#pragma unroll
  for (int mt = 0; mt < 4; ++mt) {
#pragma unroll
    for (int i = 0; i < 4; ++i) {
      const int mm = m0 + wm*64 + mt*16 + cr + i;
#pragma unroll
      for (int nt = 0; nt < TNW; ++nt) {
        const int nn = n0 + wn*(TNW*16) + nt*16 + cc;
        float v = acc[mt][nt][i];
        const long long co = sC*z + (long long)mm*ldc + nn;
        if (EPI == 0) {
          v *= scale;
          if (cbias) v += cbias[sCb*z + nn];
          ((bf16*)Cout)[co] = f2b(v);
        } else if (EPI == 1) {
          ((float*)Cout)[co] = v;
        } else {
          ((float*)Cout)[co] = fmaxf(v*rs[mm] + rsh[mm], 0.f);
        }
      }
    }
  }
}

// ---- per-row (contiguous, len 2048) mean/std, ddof=1 -----------------------
__global__ void __launch_bounds__(256) row_stats_k(const float* __restrict__ X,
    float* __restrict__ Mo, float* __restrict__ So)
{
  __shared__ float r1[4], r2[4];
  const long long row = blockIdx.x;
  const float* x = X + row*T_;
  float s1 = 0.f, s2 = 0.f;
  for (int i = threadIdx.x; i < T_; i += 256){ float v = x[i]; s1 += v; s2 += v*v; }
  s1 = wave_sum(s1); s2 = wave_sum(s2);
  const int lane = threadIdx.x & 63, w = threadIdx.x >> 6;
  if (!lane){ r1[w] = s1; r2[w] = s2; }
  __syncthreads();
  if (threadIdx.x == 0){
    s1 = r1[0]+r1[1]+r1[2]+r1[3];
    s2 = r2[0]+r2[1]+r2[2]+r2[3];
    float m = s1 * (1.f/T_);
    float var = (s2 - s1*m) * (1.f/(T_-1));
    Mo[row] = m; So[row] = sqrtf(fmaxf(var, 0.f));
  }
}

// ---- per-(b,t) mean/std over channels (strided), ddof=1 --------------------
__global__ void __launch_bounds__(256) col_stats_k(const float* __restrict__ X,
    float* __restrict__ Mo, float* __restrict__ So)
{
  __shared__ float r1[4][64], r2[4][64];
  const int b = blockIdx.y, t0 = blockIdx.x*64;
  const int tl = threadIdx.x & 63, cg = threadIdx.x >> 6;
  float s1 = 0.f, s2 = 0.f;
  for (int c = cg; c < C_; c += 4) {
    float v = X[((long long)b*C_ + c)*T_ + t0 + tl];
    s1 += v; s2 += v*v;
  }
  r1[cg][tl] = s1; r2[cg][tl] = s2;
  __syncthreads();
  if (cg == 0) {
    s1 = r1[0][tl]+r1[1][tl]+r1[2][tl]+r1[3][tl];
    s2 = r2[0][tl]+r2[1][tl]+r2[2][tl]+r2[3][tl];
    float m = s1 * (1.f/C_);
    float var = (s2 - s1*m) * (1.f/(C_-1));
    Mo[b*T_ + t0 + tl] = m;
    So[b*T_ + t0 + tl] = sqrtf(fmaxf(var, 0.f));
  }
}

// ---- transpose [C,T]->[T,C] + write tinorm & inorm normalized bf16 ---------
__global__ void __launch_bounds__(256) transform_src_k(const float* __restrict__ src,
    const float* __restrict__ tnm, const float* __restrict__ tns,
    const float* __restrict__ inm, const float* __restrict__ ins,
    bf16* __restrict__ NSt, bf16* __restrict__ NSc)
{
  __shared__ float tile[32][33];
  const int b = blockIdx.z, t0 = blockIdx.x*32, c0 = blockIdx.y*32;
  const int tx = threadIdx.x, ty = threadIdx.y;
#pragma unroll
  for (int r = 0; r < 4; ++r) {
    int ci = ty + r*8;
    tile[ci][tx] = src[((long long)b*C_ + c0 + ci)*T_ + t0 + tx];
  }
  __syncthreads();
#pragma unroll
  for (int r = 0; r < 4; ++r) {
    int tj = ty + r*8, ci = tx;
    float v = tile[ci][tj];
    int gt = t0 + tj, gc = c0 + ci;
    float a = (v - tnm[b*T_ + gt]) / (tns[b*T_ + gt] + EPSF);
    float d = (v - inm[b*C_ + gc]) / (ins[b*C_ + gc] + EPSF);
    long long o = ((long long)b*T_ + gt)*C_ + gc;
    NSt[o] = f2b(a);
    NSc[o] = f2b(d);
  }
}

__global__ void __launch_bounds__(256) transform_trg_k(const float* __restrict__ trg,
    const float* __restrict__ tnm, const float* __restrict__ tns,
    const float* __restrict__ inm, const float* __restrict__ ins,
    bf16* __restrict__ NTt, bf16* __restrict__ NTc, bf16* __restrict__ TTr)
{
  __shared__ float tile[32][33];
  const int b = blockIdx.z, t0 = blockIdx.x*32, c0 = blockIdx.y*32;
  const int tx = threadIdx.x, ty = threadIdx.y;
#pragma unroll
  for (int r = 0; r < 4; ++r) {
    int ci = ty + r*8;
    tile[ci][tx] = trg[((long long)b*C_ + c0 + ci)*T_ + t0 + tx];
  }
  __syncthreads();
#pragma unroll
  for (int r = 0; r < 4; ++r) {
    int tj = ty + r*8, ci = tx;
    float v = tile[ci][tj];
    int gt = t0 + tj, gc = c0 + ci;
    float a = (v - tnm[b*T_ + gt]) / (tns[b*T_ + gt] + EPSF);
    float d = (v - inm[b*C_ + gc]) / (ins[b*C_ + gc] + EPSF);
    long long o = ((long long)b*T_ + gt)*C_ + gc;
    NTt[o] = f2b(a);
    NTc[o] = f2b(d);
    TTr[o] = f2b(v);
  }
}

// ---- in-place bf16 row softmax over 2048 -----------------------------------
__global__ void __launch_bounds__(256) softmax_inplace_k(bf16* __restrict__ P)
{
  __shared__ float red[4];
  const long long row = blockIdx.x;
  bf16* x = P + row*T_ + threadIdx.x*8;
  bf16x8 a = *(const bf16x8*)x;
  float v[8];
#pragma unroll
  for (int j = 0; j < 8; ++j) v[j] = b2f(a[j]);
  float m = -3.4e38f;
#pragma unroll
  for (int j = 0; j < 8; ++j) m = fmaxf(m, v[j]);
  m = wave_max(m);
  const int lane = threadIdx.x & 63, w = threadIdx.x >> 6;
  if (!lane) red[w] = m;
  __syncthreads();
  m = fmaxf(fmaxf(red[0], red[1]), fmaxf(red[2], red[3]));
  __syncthreads();
  float s = 0.f;
#pragma unroll
  for (int j = 0; j < 8; ++j){ v[j] = __expf(v[j] - m); s += v[j]; }
  s = wave_sum(s);
  if (!lane) red[w] = s;
  __syncthreads();
  s = red[0]+red[1]+red[2]+red[3];
  const float inv = 1.f/s;
#pragma unroll
  for (int j = 0; j < 8; ++j) a[j] = f2b(v[j]*inv);
  *(bf16x8*)x = a;
}

// ---- fp32 row softmax (SAP) ------------------------------------------------
__global__ void __launch_bounds__(256) softmax_row_k(const float* __restrict__ X, float* __restrict__ O)
{
  __shared__ float red[4];
  const long long row = blockIdx.x;
  const float* x = X + row*T_ + threadIdx.x*8;
  float v[8];
  f32x4 a0 = *(const f32x4*)x;
  f32x4 a1 = *(const f32x4*)(x + 4);
#pragma unroll
  for (int j = 0; j < 4; ++j){ v[j] = a0[j]; v[4+j] = a1[j]; }
  float m = -3.4e38f;
#pragma unroll
  for (int j = 0; j < 8; ++j) m = fmaxf(m, v[j]);
  m = wave_max(m);
  const int lane = threadIdx.x & 63, w = threadIdx.x >> 6;
  if (!lane) red[w] = m;
  __syncthreads();
  m = fmaxf(fmaxf(red[0], red[1]), fmaxf(red[2], red[3]));
  __syncthreads();
  float s = 0.f;
#pragma unroll
  for (int j = 0; j < 8; ++j){ v[j] = __expf(v[j] - m); s += v[j]; }
  s = wave_sum(s);
  if (!lane) red[w] = s;
  __syncthreads();
  s = red[0]+red[1]+red[2]+red[3];
  const float inv = 1.f/s;
  float* o = O + row*T_ + threadIdx.x*8;
#pragma unroll
  for (int j = 0; j < 8; ++j) o[j] = v[j]*inv;
}

// ---- column sums of P over s (chunked, atomic), z in [0,2B) ----------------
__global__ void __launch_bounds__(256) colsum_k(const bf16* __restrict__ P, float* __restrict__ cs)
{
  const int t = blockIdx.x*256 + threadIdx.x;
  const int z = blockIdx.z;
  const long long s0 = (long long)blockIdx.y*256;
  const bf16* p = P + ((long long)z*S_ + s0)*T_ + t;
  float a = 0.f;
  for (int s = 0; s < 256; ++s) a += b2f(p[(long long)s*T_]);
  atomicAdd(&cs[z*T_ + t], a);
}

// ---- vv-GEMV + finalize mean_c / std_c, z in [0,2B) ------------------------
__global__ void __launch_bounds__(256) vv_fin_k(const float* __restrict__ cs,
    const bf16* __restrict__ VT, const float* __restrict__ msum,
    const float* __restrict__ m2sum, float* __restrict__ meanc, float* __restrict__ stdc)
{
  __shared__ float r1[4];
  const int c = blockIdx.x, z = blockIdx.y;
  const bf16* vr = VT + ((long long)z*C_ + c)*T_;
  const float* w = cs + z*T_;
  float a = 0.f;
  for (int t = threadIdx.x; t < T_; t += 256){ float v = b2f(vr[t]); a += w[t]*v*v; }
  a = wave_sum(a);
  const int lane = threadIdx.x & 63, wq = threadIdx.x >> 6;
  if (!lane) r1[wq] = a;
  __syncthreads();
  if (threadIdx.x == 0){
    a = r1[0]+r1[1]+r1[2]+r1[3];
    const int idx = z*C_ + c;
    meanc[idx] = msum[idx] * (1.f/S_);
    float var = (a - m2sum[idx]) * (1.f/S_);
    stdc[idx] = sqrtf(fmaxf(var, 0.f));
  }
}

// ---- fold adaptive-norm epilogue + concat into conv1 weights ---------------
__global__ void __launch_bounds__(256) weff_k(const float* __restrict__ w1,
    const float* __restrict__ b1, const float* __restrict__ sdt, const float* __restrict__ sdc,
    const float* __restrict__ mct, const float* __restrict__ mcc,
    bf16* __restrict__ Weff, float* __restrict__ beff)
{
  __shared__ float r1[4];
  const int o = blockIdx.x, b = blockIdx.y;
  float accb = 0.f;
  for (int c = threadIdx.x; c < C_; c += 256) {
    float wa = w1[o*2*C_ + c], wb = w1[o*2*C_ + C_ + c];
    Weff[((long long)(b*C_ + o))*C_ + c] = f2b(wa*sdt[b*C_+c] + wb*sdc[b*C_+c]);
    accb += wa*mct[b*C_+c] + wb*mcc[b*C_+c];
  }
  accb = wave_sum(accb);
  const int lane = threadIdx.x & 63, w = threadIdx.x >> 6;
  if (!lane) r1[w] = accb;
  __syncthreads();
  if (threadIdx.x == 0) beff[b*C_ + o] = b1[o] + r1[0]+r1[1]+r1[2]+r1[3];
}

// ---- conv2 weight reorder (k = dt*C + c) + BN scale/shift ------------------
__global__ void __launch_bounds__(256) w2r_k(const float* __restrict__ w2,
    const float* __restrict__ g, const float* __restrict__ be,
    const float* __restrict__ mu, const float* __restrict__ va,
    bf16* __restrict__ W2r, float* __restrict__ bnsc, float* __restrict__ bnsh)
{
  const int o = blockIdx.x;
  for (int c = threadIdx.x; c < C_; c += 256)
#pragma unroll
    for (int dt = 0; dt < 3; ++dt)
      W2r[(long long)o*3*C_ + dt*C_ + c] = f2b(w2[((long long)o*C_ + c)*3 + dt]);
  if (threadIdx.x == 0) {
    float s = g[o] * rsqrtf(va[o] + EPSF);
    bnsc[o] = s;
    bnsh[o] = be[o] - mu[o]*s;
  }
}

// ---- cast projection weights to bf16, order [wq_c,wq_t,wk_c,wk_t,wv_c,wv_t],
//      with 1/temp folded into both wq ---------------------------------------
__global__ void __launch_bounds__(256) cast6_k(const float* __restrict__ a0,
    const float* __restrict__ a1, const float* __restrict__ a2, const float* __restrict__ a3,
    const float* __restrict__ a4, const float* __restrict__ a5, bf16* __restrict__ o)
{
  const int i = blockIdx.x*256 + threadIdx.x;   // 6*262144 total
  const int slot = i >> 18;
  const float* srcs[6] = {a0,a1,a2,a3,a4,a5};
  const float sc = (slot < 2) ? 0.044194173824159216f : 1.f;
  o[i] = f2b(srcs[slot][i & 262143] * sc);
}

// ---- zero pad rows of x1p --------------------------------------------------
__global__ void __launch_bounds__(256) zero_pad_k(bf16* __restrict__ x1p)
{
  const int i = blockIdx.x*256 + threadIdx.x;   // 4096
  const int b = i >> 10, rem = i & 1023;
  const long long row = (rem >> 9) ? (T_+1) : 0;
  const int c = rem & (C_-1);
  x1p[((long long)b*(T_+2) + row)*C_ + c] = f2b(0.f);
}

__global__ void __launch_bounds__(256) zero_f32_k(float* __restrict__ p)
{
  p[blockIdx.x*256 + threadIdx.x] = 0.f;
}

// ---- SAP: logits -----------------------------------------------------------
__global__ void __launch_bounds__(256) sap_logit_k(const float* __restrict__ x,
    const float* __restrict__ w, const float* __restrict__ bias, float* __restrict__ out)
{
  const int n = blockIdx.x*4 + (threadIdx.x >> 6);
  const int b = blockIdx.y;
  const int lane = threadIdx.x & 63;
  const float* p = x + ((long long)b*S_ + n)*C_;
  float a = 0.f;
  for (int c = lane; c < C_; c += 64) a += p[c]*w[c];
  a = wave_sum(a);
  if (!lane) out[b*S_ + n] = a + bias[0];
}

// ---- SAP: weighted sum over n (chunked, atomic) ----------------------------
__global__ void __launch_bounds__(256) sap_wsum_k(const float* __restrict__ x,
    const float* __restrict__ a, float* __restrict__ out)
{
  const int c = blockIdx.x*256 + threadIdx.x;
  const int b = blockIdx.z;
  const long long n0 = (long long)blockIdx.y*256;
  const float* p = x + ((long long)b*S_ + n0)*C_ + c;
  const float* aw = a + b*S_ + n0;
  float acc = 0.f;
  for (int n = 0; n < 256; ++n) acc += p[(long long)n*C_] * aw[n];
  atomicAdd(&out[b*C_ + c], acc);
}

// ---- final: inorm(y)*sap_std + sap_mean ------------------------------------
__global__ void __launch_bounds__(256) final_k(const float* __restrict__ y,
    const float* __restrict__ ym, const float* __restrict__ ys,
    const float* __restrict__ sm, const float* __restrict__ ss,
    float* __restrict__ out)
{
  const long long i = (long long)(blockIdx.x*256 + threadIdx.x) * 4;
  const long long r = i >> 11;
  const float m = ym[r], inv = 1.f/(ys[r] + EPSF);
  const float sd = ss[r], mn = sm[r];
  const f32x4 v = *(const f32x4*)(y + i);
  f32x4 o;
#pragma unroll
  for (int j = 0; j < 4; ++j) o[j] = (v[j] - m)*inv*sd + mn;
  *(f32x4*)(out + i) = o;
}

// ---------------------------------------------------------------------------
extern "C" void kernel_launch(void* const* d_in, const int* in_sizes, int n_in,
                              void* d_out, int out_size, void* d_ws, size_t ws_size,
                              hipStream_t stream)
{
  (void)in_sizes; (void)n_in; (void)out_size; (void)ws_size;
  const float* src    = (const float*)d_in[0];
  const float* trg    = (const float*)d_in[1];
  const float* means  = (const float*)d_in[2];
  const float* stds   = (const float*)d_in[3];
  const float* conv1w = (const float*)d_in[10];
  const float* conv1b = (const float*)d_in[11];
  const float* conv2w = (const float*)d_in[12];
  const float* bn_g   = (const float*)d_in[13];
  const float* bn_b   = (const float*)d_in[14];
  const float* bn_m   = (const float*)d_in[15];
  const float* bn_v   = (const float*)d_in[16];
  const float* msap_w = (const float*)d_in[17];
  const float* msap_b = (const float*)d_in[18];
  const float* ssap_w = (const float*)d_in[19];
  const float* ssap_b = (const float*)d_in[20];

  const long long BTC = (long long)B_*T_*C_;   // 4194304 elems

  char* p = (char*)d_ws;
  auto take = [&](size_t n)->char*{ char* r = p; p += (n + 255) & ~(size_t)255; return r; };

  // Phase convention: p=0 -> CAN (inorm), p=1 -> TAN (tinorm); z = p*B + b.
  // NSc must directly precede P2 so the merged QKV projection can address
  // [NSc][NSt][NTc][NTt] with one base+z*BTC.
  bf16* NSc = (bf16*)take(BTC*2);                          // 8 MB
  bf16* P2  = (bf16*)take((size_t)2*B_*S_*T_*2);           // 64 MB (logits->P)
  bf16* NSt = P2;                                          // aliases (dead
  bf16* NTc = P2 + BTC;                                    //  before QK gemm
  bf16* NTt = P2 + 2*BTC;                                  //  writes P2)
  bf16* TTr = P2 + 3*BTC;
  bf16* QK4 = (bf16*)take((size_t)4*BTC*2);                // 32 MB [Qc,Qt,Kc,Kt]
  bf16* VT2 = (bf16*)take((size_t)2*BTC*2);                // 16 MB [2][B][C][T]
  bf16* WQb = (bf16*)take((size_t)6*C_*C_*2);
  bf16* Weff= (bf16*)take((size_t)B_*C_*C_*2);
  bf16* W2r = (bf16*)take((size_t)C_*3*C_*2);
  bf16* x1p = (bf16*)take((size_t)B_*(T_+2)*C_*2);
  float* y  = (float*)take((size_t)B_*C_*T_*4);            // 16 MB
  float* colsum = (float*)take(2*B_*T_*4);                 // contiguous zero
  float* msum   = (float*)take(2*B_*C_*4);                 //  block: 24576 f
  float* m2sum  = (float*)take(2*B_*C_*4);
  float* tnm_s = (float*)take(B_*T_*4);
  float* tns_s = (float*)take(B_*T_*4);
  float* tnm_t = (float*)take(B_*T_*4);
  float* tns_t = (float*)take(B_*T_*4);
  float* inm_s = (float*)take(B_*C_*4);
  float* ins_s = (float*)take(B_*C_*4);
  float* inm_t = (float*)take(B_*C_*4);
  float* ins_t = (float*)take(B_*C_*4);
  float* meanc = (float*)take(2*B_*C_*4);                  // [2][B][C]
  float* stdc  = (float*)take(2*B_*C_*4);
  float* beff  = (float*)take(B_*C_*4);
  float* bnsc  = (float*)take(C_*4);
  float* bnsh  = (float*)take(C_*4);
  float* ym    = (float*)take(B_*C_*4);
  float* ys    = (float*)take(B_*C_*4);
  float* sapl  = (float*)take(B_*S_*4);
  float* sapa  = (float*)take(B_*S_*4);
  float* sapm  = (float*)take(B_*C_*4);                    // sapm+saps contig
  float* saps  = (float*)take(B_*C_*4);

  dim3 blk(256);

  cast6_k<<<6144, blk, 0, stream>>>((const float*)d_in[7], (const float*)d_in[4],
      (const float*)d_in[8], (const float*)d_in[5], (const float*)d_in[9],
      (const float*)d_in[6], WQb);
  w2r_k<<<C_, blk, 0, stream>>>(conv2w, bn_g, bn_b, bn_m, bn_v, W2r, bnsc, bnsh);
  row_stats_k<<<B_*C_, blk, 0, stream>>>(src, inm_s, ins_s);
  row_stats_k<<<B_*C_, blk, 0, stream>>>(trg, inm_t, ins_t);
  col_stats_k<<<dim3(T_/64, B_), blk, 0, stream>>>(src, tnm_s, tns_s);
  col_stats_k<<<dim3(T_/64, B_), blk, 0, stream>>>(trg, tnm_t, tns_t);
  transform_src_k<<<dim3(T_/32, C_/32, B_), dim3(32,8), 0, stream>>>(src, tnm_s, tns_s, inm_s, ins_s, NSt, NSc);
  transform_trg_k<<<dim3(T_/32, C_/32, B_), dim3(32,8), 0, stream>>>(trg, tnm_t, tns_t, inm_t, ins_t, NTt, NTc, TTr);
  zero_pad_k<<<16, blk, 0, stream>>>(x1p);
  zero_f32_k<<<96, blk, 0, stream>>>(colsum);     // colsum+msum+m2sum
  zero_f32_k<<<16, blk, 0, stream>>>(sapm);       // sapm+saps

  // QKV projections, both phases in one launch each.
  // z in [0,4): A = {NSc,NSt,NTc,NTt}[z], B = {wq_c,wq_t,wk_c,wk_t}[z]
  gemm_nt<0,4><<<dim3(C_/128, (B_*T_)/128, 4), blk, 0, stream>>>(NSc, WQb, QK4,
      C_, C_, C_, C_, BTC, (long long)C_*C_, BTC, 0, 1, 8, 1.f,
      nullptr, nullptr, nullptr, nullptr, nullptr);
  // V^T[z] = wv[p] @ trg[b]^T -> [C,T]; z in [0,8): p=z/4, b=z%4
  gemm_nt<0,2><<<dim3(T_/64, C_/128, 8), blk, 0, stream>>>(WQb + (size_t)4*C_*C_, TTr, VT2,
      C_, C_, C_, T_, (long long)C_*C_, (long long)T_*C_, (long long)C_*T_, 0, 4, 4, 1.f,
      nullptr, nullptr, nullptr, nullptr, nullptr);
  // logits = Q @ K^T (bf16), z in [0,8)
  gemm_nt<0,4><<<dim3(T_/128, T_/128, 8), blk, 0, stream>>>(QK4, QK4 + 2*BTC, P2,
      C_, C_, C_, T_, (long long)T_*C_, (long long)T_*C_, (long long)S_*T_, 0, 1, 8, 1.f,
      nullptr, nullptr, nullptr, nullptr, nullptr);
  softmax_inplace_k<<<2*B_*S_, blk, 0, stream>>>(P2);
  colsum_k<<<dim3(T_/256, S_/256, 8), blk, 0, stream>>>(P2, colsum);
  // PV with fused sum_s / sum_s^2 epilogue (no output tile store)
  gemm_nt<3,2><<<dim3(C_/64, S_/128, 8), blk, 0, stream>>>(P2, VT2, nullptr,
      T_, T_, T_, 0, (long long)S_*T_, (long long)C_*T_, 0, C_, 1, 8, 1.f,
      nullptr, nullptr, nullptr, msum, m2sum);
  vv_fin_k<<<dim3(C_, 2*B_), blk, 0, stream>>>(colsum, VT2, msum, m2sum, meanc, stdc);

  // conv1 folded with adaptive-norm epilogues (TAN = phase 1, CAN = phase 0)
  weff_k<<<dim3(C_, B_), blk, 0, stream>>>(conv1w, conv1b,
      stdc + B_*C_, stdc, meanc + B_*C_, meanc, Weff, beff);
  gemm_nt<0,2><<<dim3(C_/64, T_/128, B_), blk, 0, stream>>>(NSc, Weff, x1p + C_,
      C_, C_, C_, C_, (long long)T_*C_, (long long)C_*C_, (long long)(T_+2)*C_, C_,
      1, 8, 1.f, nullptr, nullptr, beff, nullptr, nullptr);
  // conv2 (k=3) as overlapping-row NT GEMM + BN+ReLU epilogue
  gemm_nt<2,2><<<dim3(T_/64, C_/128, B_), blk, 0, stream>>>(W2r, x1p, y,
      3*C_, 3*C_, C_, T_, 0, (long long)(T_+2)*C_, (long long)C_*T_, 0,
      1, 8, 1.f, bnsc, bnsh, nullptr, nullptr, nullptr);
  row_stats_k<<<B_*C_, blk, 0, stream>>>(y, ym, ys);

  sap_logit_k<<<dim3(S_/4, B_), blk, 0, stream>>>(means, msap_w, msap_b, sapl);
  softmax_row_k<<<B_, blk, 0, stream>>>(sapl, sapa);
  sap_wsum_k<<<dim3(C_/256, S_/256, B_), blk, 0, stream>>>(means, sapa, sapm);
  sap_logit_k<<<dim3(S_/4, B_), blk, 0, stream>>>(stds, ssap_w, ssap_b, sapl);
  softmax_row_k<<<B_, blk, 0, stream>>>(sapl, sapa);
  sap_wsum_k<<<dim3(C_/256, S_/256, B_), blk, 0, stream>>>(stds, sapa, saps);

  final_k<<<4096, blk, 0, stream>>>(y, ym, ys, sapm, saps, (float*)d_out);
}

// Round 3
// 463.851 us; speedup vs baseline: 1.4233x; 1.2177x over previous
//
#include <hip/hip_runtime.h>
#include <cstdint>
#include <cstddef>

#define B_ 4
#define C_ 512
#define T_ 2048
#define S_ 2048
#define EPSF 1e-5f

typedef __bf16 bf16;
typedef __attribute__((ext_vector_type(8))) __bf16 bf16x8;
typedef __attribute__((ext_vector_type(4))) float f32x4;

__device__ __forceinline__ bf16 f2b(float f){ return (bf16)f; }
__device__ __forceinline__ float b2f(bf16 h){ return (float)h; }

__device__ __forceinline__ void gl_lds16(const void* g, void* l){
  __builtin_amdgcn_global_load_lds((__attribute__((address_space(1))) void*)(g),
                                   (__attribute__((address_space(3))) void*)(l), 16, 0, 0);
}

__device__ __forceinline__ float wave_sum(float v){
#pragma unroll
  for (int o = 32; o; o >>= 1) v += __shfl_xor(v, o, 64);
  return v;
}
__device__ __forceinline__ float wave_max(float v){
#pragma unroll
  for (int o = 32; o; o >>= 1) v = fmaxf(v, __shfl_xor(v, o, 64));
  return v;
}

// ---------------------------------------------------------------------------
// NT GEMM: C[m,n] = sum_k A[m,k]*B[n,k], both operands k-contiguous (bf16),
// fp32 MFMA accum. Tile 128 x (TNW*32), BK=64, 256 threads (2x2 waves).
// z-batched: A offset (z/zdivA)*sA, B offset (z%zmodB)*sB, C offset z*sC.
// EPI 0: bf16 store (acc*scale + cbias[n]) ; 1: f32 store ;
// EPI 2: f32 store relu(acc*rs[m]+rsh[m]) (BN+ReLU) ;
// EPI 3: no store — atomicAdd per-column sum/sum^2 over m into osum/osum2.
// ---------------------------------------------------------------------------
template<int EPI, int TNW>
__global__ void __launch_bounds__(256) gemm_nt(
    const bf16* __restrict__ A, const bf16* __restrict__ Bm, void* __restrict__ Cout,
    int K, int lda, int ldb, int ldc,
    long long sA, long long sB, long long sC, long long sCb,
    int zdivA, int zmodB, float scale,
    const float* __restrict__ rs, const float* __restrict__ rsh,
    const float* __restrict__ cbias,
    float* __restrict__ osum, float* __restrict__ osum2)
{
  constexpr int TN = TNW*32;
  __shared__ alignas(16) bf16 lA[128*64];
  __shared__ alignas(16) bf16 lB[TN*64];
  const int tid = threadIdx.x;
  const int z = blockIdx.z;
  const bf16* Ab = A + (long long)(z / zdivA) * sA;
  const bf16* Bb = Bm + (long long)(z % zmodB) * sB;
  const int m0 = blockIdx.y*128, n0 = blockIdx.x*TN;
  const int lane = tid & 63, wvi = tid >> 6;
  const int wm = wvi >> 1, wn = wvi & 1;

  f32x4 acc[4][TNW] = {};

  // loader: thread stages one 16B chunk/iter; XOR-swizzle k-chunk by (row&7)
  const int lrow = tid >> 3;
  const int lcol = ((tid ^ lrow) & 7) * 8;
  const bf16* pa = Ab + (long long)(m0 + lrow)*lda + lcol;
  const bf16* pb = Bb + (long long)(n0 + lrow)*ldb + lcol;
  char* sa = (char*)lA + tid*16;
  char* sb = (char*)lB + tid*16;

  for (int k0 = 0; k0 < K; k0 += 64) {
#pragma unroll
    for (int it = 0; it < 4; ++it)
      gl_lds16(pa + (long long)it*32*lda + k0, sa + it*4096);
#pragma unroll
    for (int it = 0; it < TNW; ++it)
      gl_lds16(pb + (long long)it*32*ldb + k0, sb + it*4096);
    __syncthreads();
#pragma unroll
    for (int ks = 0; ks < 2; ++ks) {
      const int kq = ks*4 + (lane >> 4);
      bf16x8 af[4], bfr[TNW];
#pragma unroll
      for (int mt = 0; mt < 4; ++mt) {
        int r = wm*64 + mt*16 + (lane & 15);
        af[mt] = *(const bf16x8*)&lA[r*64 + ((kq ^ (r & 7))*8)];
      }
#pragma unroll
      for (int nt = 0; nt < TNW; ++nt) {
        int r = wn*(TNW*16) + nt*16 + (lane & 15);
        bfr[nt] = *(const bf16x8*)&lB[r*64 + ((kq ^ (r & 7))*8)];
      }
#pragma unroll
      for (int mt = 0; mt < 4; ++mt)
#pragma unroll
        for (int nt = 0; nt < TNW; ++nt)
          acc[mt][nt] = __builtin_amdgcn_mfma_f32_16x16x32_bf16(af[mt], bfr[nt], acc[mt][nt], 0, 0, 0);
    }
    __syncthreads();
  }

  if (EPI == 3) {
    // per-column (n) sum and sum^2 over the block's 128 m-rows -> atomicAdd
    __shared__ float red1[4][TNW][16], red2[4][TNW][16];
    float s1[TNW], s2[TNW];
#pragma unroll
    for (int nt = 0; nt < TNW; ++nt) {
      s1[nt] = 0.f; s2[nt] = 0.f;
#pragma unroll
      for (int mt = 0; mt < 4; ++mt)
#pragma unroll
        for (int i = 0; i < 4; ++i) {
          float v = acc[mt][nt][i];
          s1[nt] += v; s2[nt] += v*v;
        }
      s1[nt] += __shfl_xor(s1[nt], 16, 64);
      s1[nt] += __shfl_xor(s1[nt], 32, 64);
      s2[nt] += __shfl_xor(s2[nt], 16, 64);
      s2[nt] += __shfl_xor(s2[nt], 32, 64);
    }
    if (lane < 16) {
#pragma unroll
      for (int nt = 0; nt < TNW; ++nt) {
        red1[wvi][nt][lane] = s1[nt];
        red2[wvi][nt][lane] = s2[nt];
      }
    }
    __syncthreads();
    if (tid < 2*TN) {
      const int which = tid >= TN;
      const int col = tid - which*TN;
      const int wn2 = col / (TNW*16), rem = col % (TNW*16);
      const float* rr = which ? &red2[0][0][0] : &red1[0][0][0];
      float v = rr[wn2*(TNW*16) + rem] + rr[(2+wn2)*(TNW*16) + rem];
      float* dst = which ? osum2 : osum;
      atomicAdd(&dst[sCb*z + n0 + col], v);
    }
    return;
  }

  const int cr = (lane >> 4)*4, cc = lane & 15;
#pragma unroll
  for (int mt = 0; mt < 4; ++mt) {
#pragma unroll
    for (int i = 0; i < 4; ++i) {
      const int mm = m0 + wm*64 + mt*16 + cr + i;
#pragma unroll
      for (int nt = 0; nt < TNW; ++nt) {
        const int nn = n0 + wn*(TNW*16) + nt*16 + cc;
        float v = acc[mt][nt][i];
        const long long co = sC*z + (long long)mm*ldc + nn;
        if (EPI == 0) {
          v *= scale;
          if (cbias) v += cbias[sCb*z + nn];
          ((bf16*)Cout)[co] = f2b(v);
        } else if (EPI == 1) {
          ((float*)Cout)[co] = v;
        } else {
          ((float*)Cout)[co] = fmaxf(v*rs[mm] + rsh[mm], 0.f);
        }
      }
    }
  }
}

// ---- per-row (contiguous, len 2048) mean/std, ddof=1; rows<n1 from X1 ------
__global__ void __launch_bounds__(256) row_stats_k(const float* __restrict__ X1,
    const float* __restrict__ X2, float* __restrict__ Mo, float* __restrict__ So, int n1)
{
  __shared__ float r1[4], r2[4];
  const int row = blockIdx.x;
  const float* x = (row < n1) ? X1 + (long long)row*T_ : X2 + (long long)(row-n1)*T_;
  float s1 = 0.f, s2 = 0.f;
  for (int i = threadIdx.x; i < T_; i += 256){ float v = x[i]; s1 += v; s2 += v*v; }
  s1 = wave_sum(s1); s2 = wave_sum(s2);
  const int lane = threadIdx.x & 63, w = threadIdx.x >> 6;
  if (!lane){ r1[w] = s1; r2[w] = s2; }
  __syncthreads();
  if (threadIdx.x == 0){
    s1 = r1[0]+r1[1]+r1[2]+r1[3];
    s2 = r2[0]+r2[1]+r2[2]+r2[3];
    float m = s1 * (1.f/T_);
    float var = (s2 - s1*m) * (1.f/(T_-1));
    Mo[row] = m; So[row] = sqrtf(fmaxf(var, 0.f));
  }
}

// ---- per-(b,t) mean/std over channels, src (z<B) / trg (z>=B), ddof=1 ------
__global__ void __launch_bounds__(256) col_stats_k(const float* __restrict__ src,
    const float* __restrict__ trg, float* __restrict__ Mo, float* __restrict__ So)
{
  __shared__ float r1[4][64], r2[4][64];
  const int z = blockIdx.y, t0 = blockIdx.x*64;
  const float* X = (z < B_) ? src : trg;
  const int b = z & (B_-1);
  const int tl = threadIdx.x & 63, cg = threadIdx.x >> 6;
  float s1 = 0.f, s2 = 0.f;
  for (int c = cg; c < C_; c += 4) {
    float v = X[((long long)b*C_ + c)*T_ + t0 + tl];
    s1 += v; s2 += v*v;
  }
  r1[cg][tl] = s1; r2[cg][tl] = s2;
  __syncthreads();
  if (cg == 0) {
    s1 = r1[0][tl]+r1[1][tl]+r1[2][tl]+r1[3][tl];
    s2 = r2[0][tl]+r2[1][tl]+r2[2][tl]+r2[3][tl];
    float m = s1 * (1.f/C_);
    float var = (s2 - s1*m) * (1.f/(C_-1));
    Mo[z*T_ + t0 + tl] = m;
    So[z*T_ + t0 + tl] = sqrtf(fmaxf(var, 0.f));
  }
}

// ---- transpose [C,T]->[T,C] + write tinorm & inorm bf16 (src & trg) --------
__global__ void __launch_bounds__(256) transform_k(const float* __restrict__ src,
    const float* __restrict__ trg,
    const float* __restrict__ tnm, const float* __restrict__ tns,
    const float* __restrict__ inm, const float* __restrict__ ins,
    bf16* __restrict__ NSt, bf16* __restrict__ NSc,
    bf16* __restrict__ NTt, bf16* __restrict__ NTc, bf16* __restrict__ TTr)
{
  __shared__ float tile[32][33];
  const int z = blockIdx.z, t0 = blockIdx.x*32, c0 = blockIdx.y*32;
  const int is_t = z >= B_, b = z & (B_-1);
  const float* X = is_t ? trg : src;
  const int tx = threadIdx.x, ty = threadIdx.y;
#pragma unroll
  for (int r = 0; r < 4; ++r) {
    int ci = ty + r*8;
    tile[ci][tx] = X[((long long)b*C_ + c0 + ci)*T_ + t0 + tx];
  }
  __syncthreads();
#pragma unroll
  for (int r = 0; r < 4; ++r) {
    int tj = ty + r*8, ci = tx;
    float v = tile[ci][tj];
    int gt = t0 + tj, gc = c0 + ci;
    float a = (v - tnm[z*T_ + gt]) / (tns[z*T_ + gt] + EPSF);
    float d = (v - inm[z*C_ + gc]) / (ins[z*C_ + gc] + EPSF);
    long long o = ((long long)b*T_ + gt)*C_ + gc;
    if (is_t) { NTt[o] = f2b(a); NTc[o] = f2b(d); TTr[o] = f2b(v); }
    else      { NSt[o] = f2b(a); NSc[o] = f2b(d); }
  }
}

// ---- in-place bf16 row softmax over 2048 -----------------------------------
__global__ void __launch_bounds__(256) softmax_inplace_k(bf16* __restrict__ P)
{
  __shared__ float red[4];
  const long long row = blockIdx.x;
  bf16* x = P + row*T_ + threadIdx.x*8;
  bf16x8 a = *(const bf16x8*)x;
  float v[8];
#pragma unroll
  for (int j = 0; j < 8; ++j) v[j] = b2f(a[j]);
  float m = -3.4e38f;
#pragma unroll
  for (int j = 0; j < 8; ++j) m = fmaxf(m, v[j]);
  m = wave_max(m);
  const int lane = threadIdx.x & 63, w = threadIdx.x >> 6;
  if (!lane) red[w] = m;
  __syncthreads();
  m = fmaxf(fmaxf(red[0], red[1]), fmaxf(red[2], red[3]));
  __syncthreads();
  float s = 0.f;
#pragma unroll
  for (int j = 0; j < 8; ++j){ v[j] = __expf(v[j] - m); s += v[j]; }
  s = wave_sum(s);
  if (!lane) red[w] = s;
  __syncthreads();
  s = red[0]+red[1]+red[2]+red[3];
  const float inv = 1.f/s;
#pragma unroll
  for (int j = 0; j < 8; ++j) a[j] = f2b(v[j]*inv);
  *(bf16x8*)x = a;
}

// ---- fp32 row softmax (SAP) ------------------------------------------------
__global__ void __launch_bounds__(256) softmax_row_k(const float* __restrict__ X, float* __restrict__ O)
{
  __shared__ float red[4];
  const long long row = blockIdx.x;
  const float* x = X + row*T_ + threadIdx.x*8;
  float v[8];
  f32x4 a0 = *(const f32x4*)x;
  f32x4 a1 = *(const f32x4*)(x + 4);
#pragma unroll
  for (int j = 0; j < 4; ++j){ v[j] = a0[j]; v[4+j] = a1[j]; }
  float m = -3.4e38f;
#pragma unroll
  for (int j = 0; j < 8; ++j) m = fmaxf(m, v[j]);
  m = wave_max(m);
  const int lane = threadIdx.x & 63, w = threadIdx.x >> 6;
  if (!lane) red[w] = m;
  __syncthreads();
  m = fmaxf(fmaxf(red[0], red[1]), fmaxf(red[2], red[3]));
  __syncthreads();
  float s = 0.f;
#pragma unroll
  for (int j = 0; j < 8; ++j){ v[j] = __expf(v[j] - m); s += v[j]; }
  s = wave_sum(s);
  if (!lane) red[w] = s;
  __syncthreads();
  s = red[0]+red[1]+red[2]+red[3];
  const float inv = 1.f/s;
  float* o = O + row*T_ + threadIdx.x*8;
#pragma unroll
  for (int j = 0; j < 8; ++j) o[j] = v[j]*inv;
}

// ---- column sums of P over s (chunked, atomic), z in [0,2B) ----------------
__global__ void __launch_bounds__(256) colsum_k(const bf16* __restrict__ P, float* __restrict__ cs)
{
  const int t = blockIdx.x*256 + threadIdx.x;
  const int z = blockIdx.z;
  const long long s0 = (long long)blockIdx.y*256;
  const bf16* p = P + ((long long)z*S_ + s0)*T_ + t;
  float a = 0.f;
  for (int s = 0; s < 256; ++s) a += b2f(p[(long long)s*T_]);
  atomicAdd(&cs[z*T_ + t], a);
}

// ---- vv-GEMV + finalize mean_c / std_c, z in [0,2B) ------------------------
__global__ void __launch_bounds__(256) vv_fin_k(const float* __restrict__ cs,
    const bf16* __restrict__ VT, const float* __restrict__ msum,
    const float* __restrict__ m2sum, float* __restrict__ meanc, float* __restrict__ stdc)
{
  __shared__ float r1[4];
  const int c = blockIdx.x, z = blockIdx.y;
  const bf16* vr = VT + ((long long)z*C_ + c)*T_;
  const float* w = cs + z*T_;
  float a = 0.f;
  for (int t = threadIdx.x; t < T_; t += 256){ float v = b2f(vr[t]); a += w[t]*v*v; }
  a = wave_sum(a);
  const int lane = threadIdx.x & 63, wq = threadIdx.x >> 6;
  if (!lane) r1[wq] = a;
  __syncthreads();
  if (threadIdx.x == 0){
    a = r1[0]+r1[1]+r1[2]+r1[3];
    const int idx = z*C_ + c;
    meanc[idx] = msum[idx] * (1.f/S_);
    float var = (a - m2sum[idx]) * (1.f/S_);
    stdc[idx] = sqrtf(fmaxf(var, 0.f));
  }
}

// ---- fold adaptive-norm epilogue + concat into conv1 weights ---------------
__global__ void __launch_bounds__(256) weff_k(const float* __restrict__ w1,
    const float* __restrict__ b1, const float* __restrict__ sdt, const float* __restrict__ sdc,
    const float* __restrict__ mct, const float* __restrict__ mcc,
    bf16* __restrict__ Weff, float* __restrict__ beff)
{
  __shared__ float r1[4];
  const int o = blockIdx.x, b = blockIdx.y;
  float accb = 0.f;
  for (int c = threadIdx.x; c < C_; c += 256) {
    float wa = w1[o*2*C_ + c], wb = w1[o*2*C_ + C_ + c];
    Weff[((long long)(b*C_ + o))*C_ + c] = f2b(wa*sdt[b*C_+c] + wb*sdc[b*C_+c]);
    accb += wa*mct[b*C_+c] + wb*mcc[b*C_+c];
  }
  accb = wave_sum(accb);
  const int lane = threadIdx.x & 63, w = threadIdx.x >> 6;
  if (!lane) r1[w] = accb;
  __syncthreads();
  if (threadIdx.x == 0) beff[b*C_ + o] = b1[o] + r1[0]+r1[1]+r1[2]+r1[3];
}

// ---- conv2 weight reorder (k = dt*C + c) + BN scale/shift ------------------
__global__ void __launch_bounds__(256) w2r_k(const float* __restrict__ w2,
    const float* __restrict__ g, const float* __restrict__ be,
    const float* __restrict__ mu, const float* __restrict__ va,
    bf16* __restrict__ W2r, float* __restrict__ bnsc, float* __restrict__ bnsh)
{
  const int o = blockIdx.x;
  for (int c = threadIdx.x; c < C_; c += 256)
#pragma unroll
    for (int dt = 0; dt < 3; ++dt)
      W2r[(long long)o*3*C_ + dt*C_ + c] = f2b(w2[((long long)o*C_ + c)*3 + dt]);
  if (threadIdx.x == 0) {
    float s = g[o] * rsqrtf(va[o] + EPSF);
    bnsc[o] = s;
    bnsh[o] = be[o] - mu[o]*s;
  }
}

// ---- cast projection weights to bf16, order [wq_c,wq_t,wk_c,wk_t,wv_c,wv_t],
//      with 1/temp folded into both wq ---------------------------------------
__global__ void __launch_bounds__(256) cast6_k(const float* __restrict__ a0,
    const float* __restrict__ a1, const float* __restrict__ a2, const float* __restrict__ a3,
    const float* __restrict__ a4, const float* __restrict__ a5, bf16* __restrict__ o)
{
  const int i = blockIdx.x*256 + threadIdx.x;   // 6*262144 total
  const int slot = i >> 18;
  const float* srcs[6] = {a0,a1,a2,a3,a4,a5};
  const float sc = (slot < 2) ? 0.044194173824159216f : 1.f;
  o[i] = f2b(srcs[slot][i & 262143] * sc);
}

// ---- zero pad rows of x1p --------------------------------------------------
__global__ void __launch_bounds__(256) zero_pad_k(bf16* __restrict__ x1p)
{
  const int i = blockIdx.x*256 + threadIdx.x;   // 4096
  const int b = i >> 10, rem = i & 1023;
  const long long row = (rem >> 9) ? (T_+1) : 0;
  const int c = rem & (C_-1);
  x1p[((long long)b*(T_+2) + row)*C_ + c] = f2b(0.f);
}

__global__ void __launch_bounds__(256) zero_f32_k(float* __restrict__ p)
{
  p[blockIdx.x*256 + threadIdx.x] = 0.f;
}

// ---- SAP: logits (means for z<B, stds for z>=B) ----------------------------
__global__ void __launch_bounds__(256) sap_logit_k(const float* __restrict__ means,
    const float* __restrict__ stds, const float* __restrict__ mw, const float* __restrict__ sw,
    const float* __restrict__ mb, const float* __restrict__ sb, float* __restrict__ out)
{
  const int n = blockIdx.x*4 + (threadIdx.x >> 6);
  const int z = blockIdx.y;
  const int sel = z >= B_, b = z & (B_-1);
  const float* x = sel ? stds : means;
  const float* w = sel ? sw : mw;
  const int lane = threadIdx.x & 63;
  const float* p = x + ((long long)b*S_ + n)*C_;
  float a = 0.f;
  for (int c = lane; c < C_; c += 64) a += p[c]*w[c];
  a = wave_sum(a);
  if (!lane) out[z*S_ + n] = a + (sel ? sb[0] : mb[0]);
}

// ---- SAP: weighted sum over n (chunked, atomic), z in [0,2B) ---------------
__global__ void __launch_bounds__(256) sap_wsum_k(const float* __restrict__ means,
    const float* __restrict__ stds, const float* __restrict__ a, float* __restrict__ out)
{
  const int c = blockIdx.x*256 + threadIdx.x;
  const int z = blockIdx.z;
  const int sel = z >= B_, b = z & (B_-1);
  const float* x = sel ? stds : means;
  const long long n0 = (long long)blockIdx.y*256;
  const float* p = x + ((long long)b*S_ + n0)*C_ + c;
  const float* aw = a + z*S_ + n0;
  float acc = 0.f;
  for (int n = 0; n < 256; ++n) acc += p[(long long)n*C_] * aw[n];
  atomicAdd(&out[z*C_ + c], acc);
}

// ---- final: inorm(y)*sap_std + sap_mean ------------------------------------
__global__ void __launch_bounds__(256) final_k(const float* __restrict__ y,
    const float* __restrict__ ym, const float* __restrict__ ys,
    const float* __restrict__ sapms, float* __restrict__ out)
{
  const long long i = (long long)(blockIdx.x*256 + threadIdx.x) * 4;
  const long long r = i >> 11;
  const float m = ym[r], inv = 1.f/(ys[r] + EPSF);
  const float mn = sapms[r], sd = sapms[B_*C_ + r];
  const f32x4 v = *(const f32x4*)(y + i);
  f32x4 o;
#pragma unroll
  for (int j = 0; j < 4; ++j) o[j] = (v[j] - m)*inv*sd + mn;
  *(f32x4*)(out + i) = o;
}

// ---------------------------------------------------------------------------
extern "C" void kernel_launch(void* const* d_in, const int* in_sizes, int n_in,
                              void* d_out, int out_size, void* d_ws, size_t ws_size,
                              hipStream_t stream)
{
  (void)in_sizes; (void)n_in; (void)out_size; (void)ws_size;
  const float* src    = (const float*)d_in[0];
  const float* trg    = (const float*)d_in[1];
  const float* means  = (const float*)d_in[2];
  const float* stds   = (const float*)d_in[3];
  const float* conv1w = (const float*)d_in[10];
  const float* conv1b = (const float*)d_in[11];
  const float* conv2w = (const float*)d_in[12];
  const float* bn_g   = (const float*)d_in[13];
  const float* bn_b   = (const float*)d_in[14];
  const float* bn_m   = (const float*)d_in[15];
  const float* bn_v   = (const float*)d_in[16];
  const float* msap_w = (const float*)d_in[17];
  const float* msap_b = (const float*)d_in[18];
  const float* ssap_w = (const float*)d_in[19];
  const float* ssap_b = (const float*)d_in[20];

  const long long BTC = (long long)B_*T_*C_;   // 4194304 elems

  char* p = (char*)d_ws;
  auto take = [&](size_t n)->char*{ char* r = p; p += (n + 255) & ~(size_t)255; return r; };

  // Phase convention: p=0 -> CAN (inorm), p=1 -> TAN (tinorm); z = p*B + b.
  bf16* NSc = (bf16*)take(BTC*2);                          // 8 MB
  bf16* P2  = (bf16*)take((size_t)2*B_*S_*T_*2);           // 64 MB (logits->P)
  bf16* NSt = P2;                                          // aliases (dead
  bf16* NTc = P2 + BTC;                                    //  before QK gemm
  bf16* NTt = P2 + 2*BTC;                                  //  writes P2)
  bf16* TTr = P2 + 3*BTC;
  bf16* QK4 = (bf16*)take((size_t)4*BTC*2);                // 32 MB [Qc,Qt,Kc,Kt]
  bf16* VT2 = (bf16*)take((size_t)2*BTC*2);                // 16 MB [2][B][C][T]
  bf16* WQb = (bf16*)take((size_t)6*C_*C_*2);
  bf16* Weff= (bf16*)take((size_t)B_*C_*C_*2);
  bf16* W2r = (bf16*)take((size_t)C_*3*C_*2);
  bf16* x1p = (bf16*)take((size_t)B_*(T_+2)*C_*2);
  float* y  = (float*)take((size_t)B_*C_*T_*4);            // 16 MB
  // contiguous zero block: colsum(2BT) msum(2BC) m2sum(2BC) sapms(2BC)
  float* colsum = (float*)take(2*B_*T_*4);
  float* msum   = (float*)take(2*B_*C_*4);
  float* m2sum  = (float*)take(2*B_*C_*4);
  float* sapms  = (float*)take(2*B_*C_*4);
  float* tnm = (float*)take(2*B_*T_*4);
  float* tns = (float*)take(2*B_*T_*4);
  float* inm = (float*)take(2*B_*C_*4);
  float* ins = (float*)take(2*B_*C_*4);
  float* meanc = (float*)take(2*B_*C_*4);                  // [2][B][C]
  float* stdc  = (float*)take(2*B_*C_*4);
  float* beff  = (float*)take(B_*C_*4);
  float* bnsc  = (float*)take(C_*4);
  float* bnsh  = (float*)take(C_*4);
  float* ym    = (float*)take(B_*C_*4);
  float* ys    = (float*)take(B_*C_*4);
  float* sapl  = (float*)take(2*B_*S_*4);
  float* sapa  = (float*)take(2*B_*S_*4);

  dim3 blk(256);

  cast6_k<<<6144, blk, 0, stream>>>((const float*)d_in[7], (const float*)d_in[4],
      (const float*)d_in[8], (const float*)d_in[5], (const float*)d_in[9],
      (const float*)d_in[6], WQb);
  w2r_k<<<C_, blk, 0, stream>>>(conv2w, bn_g, bn_b, bn_m, bn_v, W2r, bnsc, bnsh);
  row_stats_k<<<2*B_*C_, blk, 0, stream>>>(src, trg, inm, ins, B_*C_);
  col_stats_k<<<dim3(T_/64, 2*B_), blk, 0, stream>>>(src, trg, tnm, tns);
  transform_k<<<dim3(T_/32, C_/32, 2*B_), dim3(32,8), 0, stream>>>(src, trg,
      tnm, tns, inm, ins, NSt, NSc, NTt, NTc, TTr);
  zero_pad_k<<<16, blk, 0, stream>>>(x1p);
  zero_f32_k<<<112, blk, 0, stream>>>(colsum);    // colsum+msum+m2sum+sapms

  // QKV projections, both phases in one launch each.
  // z in [0,4): A = {NSc,NSt,NTc,NTt}[z], B = {wq_c,wq_t,wk_c,wk_t}[z]
  gemm_nt<0,4><<<dim3(C_/128, (B_*T_)/128, 4), blk, 0, stream>>>(NSc, WQb, QK4,
      C_, C_, C_, C_, BTC, (long long)C_*C_, BTC, 0, 1, 8, 1.f,
      nullptr, nullptr, nullptr, nullptr, nullptr);
  // V^T[z] = wv[p] @ trg[b]^T -> [C,T]; z in [0,8): p=z/4, b=z%4
  gemm_nt<0,2><<<dim3(T_/64, C_/128, 8), blk, 0, stream>>>(WQb + (size_t)4*C_*C_, TTr, VT2,
      C_, C_, C_, T_, (long long)C_*C_, (long long)T_*C_, (long long)C_*T_, 0, 4, 4, 1.f,
      nullptr, nullptr, nullptr, nullptr, nullptr);
  // logits = Q @ K^T (bf16), z in [0,8)
  gemm_nt<0,4><<<dim3(T_/128, T_/128, 8), blk, 0, stream>>>(QK4, QK4 + 2*BTC, P2,
      C_, C_, C_, T_, (long long)T_*C_, (long long)T_*C_, (long long)S_*T_, 0, 1, 8, 1.f,
      nullptr, nullptr, nullptr, nullptr, nullptr);
  softmax_inplace_k<<<2*B_*S_, blk, 0, stream>>>(P2);
  colsum_k<<<dim3(T_/256, S_/256, 8), blk, 0, stream>>>(P2, colsum);
  // PV with fused sum_s / sum_s^2 epilogue (128x128 tile: P fetched 4x not 8x)
  gemm_nt<3,4><<<dim3(C_/128, S_/128, 8), blk, 0, stream>>>(P2, VT2, nullptr,
      T_, T_, T_, 0, (long long)S_*T_, (long long)C_*T_, 0, C_, 1, 8, 1.f,
      nullptr, nullptr, nullptr, msum, m2sum);
  vv_fin_k<<<dim3(C_, 2*B_), blk, 0, stream>>>(colsum, VT2, msum, m2sum, meanc, stdc);

  // conv1 folded with adaptive-norm epilogues (TAN = phase 1, CAN = phase 0)
  weff_k<<<dim3(C_, B_), blk, 0, stream>>>(conv1w, conv1b,
      stdc + B_*C_, stdc, meanc + B_*C_, meanc, Weff, beff);
  gemm_nt<0,2><<<dim3(C_/64, T_/128, B_), blk, 0, stream>>>(NSc, Weff, x1p + C_,
      C_, C_, C_, C_, (long long)T_*C_, (long long)C_*C_, (long long)(T_+2)*C_, C_,
      1, 8, 1.f, nullptr, nullptr, beff, nullptr, nullptr);
  // conv2 (k=3) as overlapping-row NT GEMM + BN+ReLU epilogue
  gemm_nt<2,2><<<dim3(T_/64, C_/128, B_), blk, 0, stream>>>(W2r, x1p, y,
      3*C_, 3*C_, C_, T_, 0, (long long)(T_+2)*C_, (long long)C_*T_, 0,
      1, 8, 1.f, bnsc, bnsh, nullptr, nullptr, nullptr);
  row_stats_k<<<B_*C_, blk, 0, stream>>>(y, nullptr, ym, ys, B_*C_);

  sap_logit_k<<<dim3(S_/4, 2*B_), blk, 0, stream>>>(means, stds, msap_w, ssap_w,
      msap_b, ssap_b, sapl);
  softmax_row_k<<<2*B_, blk, 0, stream>>>(sapl, sapa);
  sap_wsum_k<<<dim3(C_/256, S_/256, 2*B_), blk, 0, stream>>>(means, stds, sapa, sapms);

  final_k<<<4096, blk, 0, stream>>>(y, ym, ys, sapms, (float*)d_out);
}

// Round 4
// 453.406 us; speedup vs baseline: 1.4561x; 1.0230x over previous
//
#include <hip/hip_runtime.h>
#include <cstdint>
#include <cstddef>

#define B_ 4
#define C_ 512
#define T_ 2048
#define S_ 2048
#define EPSF 1e-5f

typedef __bf16 bf16;
typedef __attribute__((ext_vector_type(8))) __bf16 bf16x8;
typedef __attribute__((ext_vector_type(4))) float f32x4;

__device__ __forceinline__ bf16 f2b(float f){ return (bf16)f; }
__device__ __forceinline__ float b2f(bf16 h){ return (float)h; }

__device__ __forceinline__ void gl_lds16(const void* g, void* l){
  __builtin_amdgcn_global_load_lds((__attribute__((address_space(1))) void*)(g),
                                   (__attribute__((address_space(3))) void*)(l), 16, 0, 0);
}

__device__ __forceinline__ float wave_sum(float v){
#pragma unroll
  for (int o = 32; o; o >>= 1) v += __shfl_xor(v, o, 64);
  return v;
}
__device__ __forceinline__ float wave_max(float v){
#pragma unroll
  for (int o = 32; o; o >>= 1) v = fmaxf(v, __shfl_xor(v, o, 64));
  return v;
}

// ---------------------------------------------------------------------------
// NT GEMM: C[m,n] = sum_k A[m,k]*B[n,k], both operands k-contiguous (bf16),
// fp32 MFMA accum. Tile 128 x (TNW*32), BK=64, 256 threads (2x2 waves).
// z-batched: A offset (z/zdivA)*sA, B offset (z%zmodB)*sB, C offset z*sC.
// EPI 0: bf16 store (acc*scale + cbias[n])
// EPI 2: f32 store relu(acc*rs[m%?]+rsh[..]) + fused per-row sum/sum^2 atomics
// EPI 3: no store — per-column sum/sum^2 over m of acc*rlinv[row] (rlinv=1/l)
// EPI 4: bf16 store exp(acc) + per-row partial-sum atomics into osum (l)
// ---------------------------------------------------------------------------
template<int EPI, int TNW>
__global__ void __launch_bounds__(256) gemm_nt(
    const bf16* __restrict__ A, const bf16* __restrict__ Bm, void* __restrict__ Cout,
    int K, int lda, int ldb, int ldc,
    long long sA, long long sB, long long sC, long long sCb,
    int zdivA, int zmodB, float scale,
    const float* __restrict__ rs, const float* __restrict__ rsh,
    const float* __restrict__ cbias,
    float* __restrict__ osum, float* __restrict__ osum2, long long sRs)
{
  constexpr int TN = TNW*32;
  __shared__ alignas(16) bf16 lA[128*64];
  __shared__ alignas(16) bf16 lB[TN*64];
  const int tid = threadIdx.x;
  const int z = blockIdx.z;
  const bf16* Ab = A + (long long)(z / zdivA) * sA;
  const bf16* Bb = Bm + (long long)(z % zmodB) * sB;
  const int m0 = blockIdx.y*128, n0 = blockIdx.x*TN;
  const int lane = tid & 63, wvi = tid >> 6;
  const int wm = wvi >> 1, wn = wvi & 1;

  f32x4 acc[4][TNW] = {};

  // loader: thread stages one 16B chunk/iter; XOR-swizzle k-chunk by (row&7)
  const int lrow = tid >> 3;
  const int lcol = ((tid ^ lrow) & 7) * 8;
  const bf16* pa = Ab + (long long)(m0 + lrow)*lda + lcol;
  const bf16* pb = Bb + (long long)(n0 + lrow)*ldb + lcol;
  char* sa = (char*)lA + tid*16;
  char* sb = (char*)lB + tid*16;

  for (int k0 = 0; k0 < K; k0 += 64) {
#pragma unroll
    for (int it = 0; it < 4; ++it)
      gl_lds16(pa + (long long)it*32*lda + k0, sa + it*4096);
#pragma unroll
    for (int it = 0; it < TNW; ++it)
      gl_lds16(pb + (long long)it*32*ldb + k0, sb + it*4096);
    __syncthreads();
#pragma unroll
    for (int ks = 0; ks < 2; ++ks) {
      const int kq = ks*4 + (lane >> 4);
      bf16x8 af[4], bfr[TNW];
#pragma unroll
      for (int mt = 0; mt < 4; ++mt) {
        int r = wm*64 + mt*16 + (lane & 15);
        af[mt] = *(const bf16x8*)&lA[r*64 + ((kq ^ (r & 7))*8)];
      }
#pragma unroll
      for (int nt = 0; nt < TNW; ++nt) {
        int r = wn*(TNW*16) + nt*16 + (lane & 15);
        bfr[nt] = *(const bf16x8*)&lB[r*64 + ((kq ^ (r & 7))*8)];
      }
#pragma unroll
      for (int mt = 0; mt < 4; ++mt)
#pragma unroll
        for (int nt = 0; nt < TNW; ++nt)
          acc[mt][nt] = __builtin_amdgcn_mfma_f32_16x16x32_bf16(af[mt], bfr[nt], acc[mt][nt], 0, 0, 0);
    }
    __syncthreads();
  }

  if (EPI == 3) {
    // per-column sum / sum^2 over m of acc * (1/l[row]); no C store.
    // reduction scratch aliased onto dead lA (loop ended with syncthreads).
    float* red1 = (float*)lA;                 // [4][TNW][16]
    float* red2 = red1 + 4*TNW*16;
    const int cr = (lane >> 4)*4;
    float linv[4][4];
#pragma unroll
    for (int mt = 0; mt < 4; ++mt)
#pragma unroll
      for (int i = 0; i < 4; ++i)
        linv[mt][i] = 1.f / rs[(long long)z*sRs + (m0 + wm*64 + mt*16 + cr + i)];
    float s1[TNW], s2[TNW];
#pragma unroll
    for (int nt = 0; nt < TNW; ++nt) {
      s1[nt] = 0.f; s2[nt] = 0.f;
#pragma unroll
      for (int mt = 0; mt < 4; ++mt)
#pragma unroll
        for (int i = 0; i < 4; ++i) {
          float v = acc[mt][nt][i] * linv[mt][i];
          s1[nt] += v; s2[nt] += v*v;
        }
      s1[nt] += __shfl_xor(s1[nt], 16, 64);
      s1[nt] += __shfl_xor(s1[nt], 32, 64);
      s2[nt] += __shfl_xor(s2[nt], 16, 64);
      s2[nt] += __shfl_xor(s2[nt], 32, 64);
    }
    if (lane < 16) {
#pragma unroll
      for (int nt = 0; nt < TNW; ++nt) {
        red1[(wvi*TNW + nt)*16 + lane] = s1[nt];
        red2[(wvi*TNW + nt)*16 + lane] = s2[nt];
      }
    }
    __syncthreads();
    if (tid < 2*TN) {
      const int which = tid >= TN;
      const int col = tid - which*TN;
      const int wn2 = col / (TNW*16), rem = col % (TNW*16);
      const float* rr = which ? red2 : red1;
      float v = rr[wn2*(TNW*16) + rem] + rr[(2+wn2)*(TNW*16) + rem];
      float* dst = which ? osum2 : osum;
      atomicAdd(&dst[sCb*z + n0 + col], v);
    }
    return;
  }

  const int cr = (lane >> 4)*4, cc = lane & 15;
#pragma unroll
  for (int mt = 0; mt < 4; ++mt) {
#pragma unroll
    for (int i = 0; i < 4; ++i) {
      const int mm = m0 + wm*64 + mt*16 + cr + i;
      float rsum = 0.f, rsum2 = 0.f;
#pragma unroll
      for (int nt = 0; nt < TNW; ++nt) {
        const int nn = n0 + wn*(TNW*16) + nt*16 + cc;
        float v = acc[mt][nt][i];
        const long long co = sC*z + (long long)mm*ldc + nn;
        if (EPI == 0) {
          v *= scale;
          if (cbias) v += cbias[sCb*z + nn];
          ((bf16*)Cout)[co] = f2b(v);
        } else if (EPI == 2) {
          v = fmaxf(v*rs[mm] + rsh[mm], 0.f);
          ((float*)Cout)[co] = v;
          rsum += v; rsum2 += v*v;
        } else if (EPI == 4) {
          v = __expf(v);
          ((bf16*)Cout)[co] = f2b(v);
          rsum += v;
        }
      }
      if (EPI == 2 || EPI == 4) {
        // reduce across the 16 cc lanes (row constant there)
        rsum += __shfl_xor(rsum, 1, 64); rsum += __shfl_xor(rsum, 2, 64);
        rsum += __shfl_xor(rsum, 4, 64); rsum += __shfl_xor(rsum, 8, 64);
        if (EPI == 2) {
          rsum2 += __shfl_xor(rsum2, 1, 64); rsum2 += __shfl_xor(rsum2, 2, 64);
          rsum2 += __shfl_xor(rsum2, 4, 64); rsum2 += __shfl_xor(rsum2, 8, 64);
        }
        if (cc == 0) {
          atomicAdd(&osum[(long long)z*sRs + mm], rsum);
          if (EPI == 2) atomicAdd(&osum2[(long long)z*sRs + mm], rsum2);
        }
      }
    }
  }
}

// ---- per-row (contiguous, len 2048) mean/std, ddof=1; rows<n1 from X1 ------
__global__ void __launch_bounds__(256) row_stats_k(const float* __restrict__ X1,
    const float* __restrict__ X2, float* __restrict__ Mo, float* __restrict__ So, int n1)
{
  __shared__ float r1[4], r2[4];
  const int row = blockIdx.x;
  const float* x = (row < n1) ? X1 + (long long)row*T_ : X2 + (long long)(row-n1)*T_;
  float s1 = 0.f, s2 = 0.f;
  for (int i = threadIdx.x; i < T_; i += 256){ float v = x[i]; s1 += v; s2 += v*v; }
  s1 = wave_sum(s1); s2 = wave_sum(s2);
  const int lane = threadIdx.x & 63, w = threadIdx.x >> 6;
  if (!lane){ r1[w] = s1; r2[w] = s2; }
  __syncthreads();
  if (threadIdx.x == 0){
    s1 = r1[0]+r1[1]+r1[2]+r1[3];
    s2 = r2[0]+r2[1]+r2[2]+r2[3];
    float m = s1 * (1.f/T_);
    float var = (s2 - s1*m) * (1.f/(T_-1));
    Mo[row] = m; So[row] = sqrtf(fmaxf(var, 0.f));
  }
}

// ---- per-(b,t) mean/std over channels, src (z<B) / trg (z>=B), ddof=1 ------
__global__ void __launch_bounds__(256) col_stats_k(const float* __restrict__ src,
    const float* __restrict__ trg, float* __restrict__ Mo, float* __restrict__ So)
{
  __shared__ float r1[4][64], r2[4][64];
  const int z = blockIdx.y, t0 = blockIdx.x*64;
  const float* X = (z < B_) ? src : trg;
  const int b = z & (B_-1);
  const int tl = threadIdx.x & 63, cg = threadIdx.x >> 6;
  float s1 = 0.f, s2 = 0.f;
  for (int c = cg; c < C_; c += 4) {
    float v = X[((long long)b*C_ + c)*T_ + t0 + tl];
    s1 += v; s2 += v*v;
  }
  r1[cg][tl] = s1; r2[cg][tl] = s2;
  __syncthreads();
  if (cg == 0) {
    s1 = r1[0][tl]+r1[1][tl]+r1[2][tl]+r1[3][tl];
    s2 = r2[0][tl]+r2[1][tl]+r2[2][tl]+r2[3][tl];
    float m = s1 * (1.f/C_);
    float var = (s2 - s1*m) * (1.f/(C_-1));
    Mo[z*T_ + t0 + tl] = m;
    So[z*T_ + t0 + tl] = sqrtf(fmaxf(var, 0.f));
  }
}

// ---- transpose [C,T]->[T,C] + write tinorm & inorm bf16 (src & trg) --------
__global__ void __launch_bounds__(256) transform_k(const float* __restrict__ src,
    const float* __restrict__ trg,
    const float* __restrict__ tnm, const float* __restrict__ tns,
    const float* __restrict__ inm, const float* __restrict__ ins,
    bf16* __restrict__ NSt, bf16* __restrict__ NSc,
    bf16* __restrict__ NTt, bf16* __restrict__ NTc, bf16* __restrict__ TTr)
{
  __shared__ float tile[32][33];
  const int z = blockIdx.z, t0 = blockIdx.x*32, c0 = blockIdx.y*32;
  const int is_t = z >= B_, b = z & (B_-1);
  const float* X = is_t ? trg : src;
  const int tx = threadIdx.x, ty = threadIdx.y;
#pragma unroll
  for (int r = 0; r < 4; ++r) {
    int ci = ty + r*8;
    tile[ci][tx] = X[((long long)b*C_ + c0 + ci)*T_ + t0 + tx];
  }
  __syncthreads();
#pragma unroll
  for (int r = 0; r < 4; ++r) {
    int tj = ty + r*8, ci = tx;
    float v = tile[ci][tj];
    int gt = t0 + tj, gc = c0 + ci;
    float a = (v - tnm[z*T_ + gt]) / (tns[z*T_ + gt] + EPSF);
    float d = (v - inm[z*C_ + gc]) / (ins[z*C_ + gc] + EPSF);
    long long o = ((long long)b*T_ + gt)*C_ + gc;
    if (is_t) { NTt[o] = f2b(a); NTc[o] = f2b(d); TTr[o] = f2b(v); }
    else      { NSt[o] = f2b(a); NSc[o] = f2b(d); }
  }
}

// ---- fp32 row softmax (SAP) ------------------------------------------------
__global__ void __launch_bounds__(256) softmax_row_k(const float* __restrict__ X, float* __restrict__ O)
{
  __shared__ float red[4];
  const long long row = blockIdx.x;
  const float* x = X + row*T_ + threadIdx.x*8;
  float v[8];
  f32x4 a0 = *(const f32x4*)x;
  f32x4 a1 = *(const f32x4*)(x + 4);
#pragma unroll
  for (int j = 0; j < 4; ++j){ v[j] = a0[j]; v[4+j] = a1[j]; }
  float m = -3.4e38f;
#pragma unroll
  for (int j = 0; j < 8; ++j) m = fmaxf(m, v[j]);
  m = wave_max(m);
  const int lane = threadIdx.x & 63, w = threadIdx.x >> 6;
  if (!lane) red[w] = m;
  __syncthreads();
  m = fmaxf(fmaxf(red[0], red[1]), fmaxf(red[2], red[3]));
  __syncthreads();
  float s = 0.f;
#pragma unroll
  for (int j = 0; j < 8; ++j){ v[j] = __expf(v[j] - m); s += v[j]; }
  s = wave_sum(s);
  if (!lane) red[w] = s;
  __syncthreads();
  s = red[0]+red[1]+red[2]+red[3];
  const float inv = 1.f/s;
  float* o = O + row*T_ + threadIdx.x*8;
#pragma unroll
  for (int j = 0; j < 8; ++j) o[j] = v[j]*inv;
}

// ---- normalized column sums of P' over s (chunked, atomic), z in [0,2B) ----
__global__ void __launch_bounds__(256) colsum_k(const bf16* __restrict__ P,
    const float* __restrict__ l, float* __restrict__ cs)
{
  __shared__ float linv[256];
  const int t = blockIdx.x*256 + threadIdx.x;
  const int z = blockIdx.z;
  const long long s0 = (long long)blockIdx.y*256;
  linv[threadIdx.x] = 1.f / l[(long long)z*S_ + s0 + threadIdx.x];
  __syncthreads();
  const bf16* p = P + ((long long)z*S_ + s0)*T_ + t;
  float a = 0.f;
  for (int s = 0; s < 256; ++s) a += b2f(p[(long long)s*T_]) * linv[s];
  atomicAdd(&cs[z*T_ + t], a);
}

// ---- vv-GEMV + finalize mean_c / std_c, z in [0,2B) ------------------------
__global__ void __launch_bounds__(256) vv_fin_k(const float* __restrict__ cs,
    const bf16* __restrict__ VT, const float* __restrict__ msum,
    const float* __restrict__ m2sum, float* __restrict__ meanc, float* __restrict__ stdc)
{
  __shared__ float r1[4];
  const int c = blockIdx.x, z = blockIdx.y;
  const bf16* vr = VT + ((long long)z*C_ + c)*T_;
  const float* w = cs + z*T_;
  float a = 0.f;
  for (int t = threadIdx.x; t < T_; t += 256){ float v = b2f(vr[t]); a += w[t]*v*v; }
  a = wave_sum(a);
  const int lane = threadIdx.x & 63, wq = threadIdx.x >> 6;
  if (!lane) r1[wq] = a;
  __syncthreads();
  if (threadIdx.x == 0){
    a = r1[0]+r1[1]+r1[2]+r1[3];
    const int idx = z*C_ + c;
    meanc[idx] = msum[idx] * (1.f/S_);
    float var = (a - m2sum[idx]) * (1.f/S_);
    stdc[idx] = sqrtf(fmaxf(var, 0.f));
  }
}

// ---- fold adaptive-norm epilogue + concat into conv1 weights ---------------
__global__ void __launch_bounds__(256) weff_k(const float* __restrict__ w1,
    const float* __restrict__ b1, const float* __restrict__ sdt, const float* __restrict__ sdc,
    const float* __restrict__ mct, const float* __restrict__ mcc,
    bf16* __restrict__ Weff, float* __restrict__ beff)
{
  __shared__ float r1[4];
  const int o = blockIdx.x, b = blockIdx.y;
  float accb = 0.f;
  for (int c = threadIdx.x; c < C_; c += 256) {
    float wa = w1[o*2*C_ + c], wb = w1[o*2*C_ + C_ + c];
    Weff[((long long)(b*C_ + o))*C_ + c] = f2b(wa*sdt[b*C_+c] + wb*sdc[b*C_+c]);
    accb += wa*mct[b*C_+c] + wb*mcc[b*C_+c];
  }
  accb = wave_sum(accb);
  const int lane = threadIdx.x & 63, w = threadIdx.x >> 6;
  if (!lane) r1[w] = accb;
  __syncthreads();
  if (threadIdx.x == 0) beff[b*C_ + o] = b1[o] + r1[0]+r1[1]+r1[2]+r1[3];
}

// ---- conv2 weight reorder (k = dt*C + c) + BN scale/shift ------------------
__global__ void __launch_bounds__(256) w2r_k(const float* __restrict__ w2,
    const float* __restrict__ g, const float* __restrict__ be,
    const float* __restrict__ mu, const float* __restrict__ va,
    bf16* __restrict__ W2r, float* __restrict__ bnsc, float* __restrict__ bnsh)
{
  const int o = blockIdx.x;
  for (int c = threadIdx.x; c < C_; c += 256)
#pragma unroll
    for (int dt = 0; dt < 3; ++dt)
      W2r[(long long)o*3*C_ + dt*C_ + c] = f2b(w2[((long long)o*C_ + c)*3 + dt]);
  if (threadIdx.x == 0) {
    float s = g[o] * rsqrtf(va[o] + EPSF);
    bnsc[o] = s;
    bnsh[o] = be[o] - mu[o]*s;
  }
}

// ---- cast projection weights to bf16, order [wq_c,wq_t,wk_c,wk_t,wv_c,wv_t],
//      with 1/temp folded into both wq ---------------------------------------
__global__ void __launch_bounds__(256) cast6_k(const float* __restrict__ a0,
    const float* __restrict__ a1, const float* __restrict__ a2, const float* __restrict__ a3,
    const float* __restrict__ a4, const float* __restrict__ a5, bf16* __restrict__ o)
{
  const int i = blockIdx.x*256 + threadIdx.x;   // 6*262144 total
  const int slot = i >> 18;
  const float* srcs[6] = {a0,a1,a2,a3,a4,a5};
  const float sc = (slot < 2) ? 0.044194173824159216f : 1.f;
  o[i] = f2b(srcs[slot][i & 262143] * sc);
}

// ---- zero pad rows of x1p --------------------------------------------------
__global__ void __launch_bounds__(256) zero_pad_k(bf16* __restrict__ x1p)
{
  const int i = blockIdx.x*256 + threadIdx.x;   // 4096
  const int b = i >> 10, rem = i & 1023;
  const long long row = (rem >> 9) ? (T_+1) : 0;
  const int c = rem & (C_-1);
  x1p[((long long)b*(T_+2) + row)*C_ + c] = f2b(0.f);
}

__global__ void __launch_bounds__(256) zero_f32_k(float* __restrict__ p)
{
  p[blockIdx.x*256 + threadIdx.x] = 0.f;
}

// ---- SAP: logits (means for z<B, stds for z>=B) ----------------------------
__global__ void __launch_bounds__(256) sap_logit_k(const float* __restrict__ means,
    const float* __restrict__ stds, const float* __restrict__ mw, const float* __restrict__ sw,
    const float* __restrict__ mb, const float* __restrict__ sb, float* __restrict__ out)
{
  const int n = blockIdx.x*4 + (threadIdx.x >> 6);
  const int z = blockIdx.y;
  const int sel = z >= B_, b = z & (B_-1);
  const float* x = sel ? stds : means;
  const float* w = sel ? sw : mw;
  const int lane = threadIdx.x & 63;
  const float* p = x + ((long long)b*S_ + n)*C_;
  float a = 0.f;
  for (int c = lane; c < C_; c += 64) a += p[c]*w[c];
  a = wave_sum(a);
  if (!lane) out[z*S_ + n] = a + (sel ? sb[0] : mb[0]);
}

// ---- SAP: weighted sum over n (chunked, atomic), z in [0,2B) ---------------
__global__ void __launch_bounds__(256) sap_wsum_k(const float* __restrict__ means,
    const float* __restrict__ stds, const float* __restrict__ a, float* __restrict__ out)
{
  const int c = blockIdx.x*256 + threadIdx.x;
  const int z = blockIdx.z;
  const int sel = z >= B_, b = z & (B_-1);
  const float* x = sel ? stds : means;
  const long long n0 = (long long)blockIdx.y*256;
  const float* p = x + ((long long)b*S_ + n0)*C_ + c;
  const float* aw = a + z*S_ + n0;
  float acc = 0.f;
  for (int n = 0; n < 256; ++n) acc += p[(long long)n*C_] * aw[n];
  atomicAdd(&out[z*C_ + c], acc);
}

// ---- final: inorm(y)*sap_std + sap_mean, stats from raw sums ---------------
__global__ void __launch_bounds__(256) final_k(const float* __restrict__ y,
    const float* __restrict__ ysum, const float* __restrict__ y2sum,
    const float* __restrict__ sapms, float* __restrict__ out)
{
  const long long i = (long long)(blockIdx.x*256 + threadIdx.x) * 4;
  const long long r = i >> 11;
  const float s1 = ysum[r], s2 = y2sum[r];
  const float m = s1 * (1.f/T_);
  const float var = (s2 - s1*m) * (1.f/(T_-1));
  const float inv = 1.f/(sqrtf(fmaxf(var, 0.f)) + EPSF);
  const float mn = sapms[r], sd = sapms[B_*C_ + r];
  const f32x4 v = *(const f32x4*)(y + i);
  f32x4 o;
#pragma unroll
  for (int j = 0; j < 4; ++j) o[j] = (v[j] - m)*inv*sd + mn;
  *(f32x4*)(out + i) = o;
}

// ---------------------------------------------------------------------------
extern "C" void kernel_launch(void* const* d_in, const int* in_sizes, int n_in,
                              void* d_out, int out_size, void* d_ws, size_t ws_size,
                              hipStream_t stream)
{
  (void)in_sizes; (void)n_in; (void)out_size; (void)ws_size;
  const float* src    = (const float*)d_in[0];
  const float* trg    = (const float*)d_in[1];
  const float* means  = (const float*)d_in[2];
  const float* stds   = (const float*)d_in[3];
  const float* conv1w = (const float*)d_in[10];
  const float* conv1b = (const float*)d_in[11];
  const float* conv2w = (const float*)d_in[12];
  const float* bn_g   = (const float*)d_in[13];
  const float* bn_b   = (const float*)d_in[14];
  const float* bn_m   = (const float*)d_in[15];
  const float* bn_v   = (const float*)d_in[16];
  const float* msap_w = (const float*)d_in[17];
  const float* msap_b = (const float*)d_in[18];
  const float* ssap_w = (const float*)d_in[19];
  const float* ssap_b = (const float*)d_in[20];

  const long long BTC = (long long)B_*T_*C_;   // 4194304 elems

  char* p = (char*)d_ws;
  auto take = [&](size_t n)->char*{ char* r = p; p += (n + 255) & ~(size_t)255; return r; };

  // Phase convention: p=0 -> CAN (inorm), p=1 -> TAN (tinorm); z = p*B + b.
  bf16* NSc = (bf16*)take(BTC*2);                          // 8 MB
  bf16* P2  = (bf16*)take((size_t)2*B_*S_*T_*2);           // 64 MB (exp logits)
  bf16* NSt = P2;                                          // aliases (dead
  bf16* NTc = P2 + BTC;                                    //  before QK gemm
  bf16* NTt = P2 + 2*BTC;                                  //  writes P2)
  bf16* TTr = P2 + 3*BTC;
  bf16* QK4 = (bf16*)take((size_t)4*BTC*2);                // 32 MB [Qc,Qt,Kc,Kt]
  bf16* VT2 = (bf16*)take((size_t)2*BTC*2);                // 16 MB [2][B][C][T]
  bf16* WQb = (bf16*)take((size_t)6*C_*C_*2);
  bf16* Weff= (bf16*)take((size_t)B_*C_*C_*2);
  bf16* W2r = (bf16*)take((size_t)C_*3*C_*2);
  bf16* x1p = (bf16*)take((size_t)B_*(T_+2)*C_*2);
  float* y  = (float*)take((size_t)B_*C_*T_*4);            // 16 MB
  // contiguous zero block: colsum, msum, m2sum, sapms, lrow, ysum, y2sum
  float* colsum = (float*)take(2*B_*T_*4);                 // 16384
  float* msum   = (float*)take(2*B_*C_*4);                 // 4096
  float* m2sum  = (float*)take(2*B_*C_*4);                 // 4096
  float* sapms  = (float*)take(2*B_*C_*4);                 // 4096
  float* lrow   = (float*)take(2*B_*S_*4);                 // 16384
  float* ysum   = (float*)take(B_*C_*4);                   // 2048
  float* y2sum  = (float*)take(B_*C_*4);                   // 2048  => 49152
  float* tnm = (float*)take(2*B_*T_*4);
  float* tns = (float*)take(2*B_*T_*4);
  float* inm = (float*)take(2*B_*C_*4);
  float* ins = (float*)take(2*B_*C_*4);
  float* meanc = (float*)take(2*B_*C_*4);                  // [2][B][C]
  float* stdc  = (float*)take(2*B_*C_*4);
  float* beff  = (float*)take(B_*C_*4);
  float* bnsc  = (float*)take(C_*4);
  float* bnsh  = (float*)take(C_*4);
  float* sapl  = (float*)take(2*B_*S_*4);
  float* sapa  = (float*)take(2*B_*S_*4);

  dim3 blk(256);

  cast6_k<<<6144, blk, 0, stream>>>((const float*)d_in[7], (const float*)d_in[4],
      (const float*)d_in[8], (const float*)d_in[5], (const float*)d_in[9],
      (const float*)d_in[6], WQb);
  w2r_k<<<C_, blk, 0, stream>>>(conv2w, bn_g, bn_b, bn_m, bn_v, W2r, bnsc, bnsh);
  row_stats_k<<<2*B_*C_, blk, 0, stream>>>(src, trg, inm, ins, B_*C_);
  col_stats_k<<<dim3(T_/64, 2*B_), blk, 0, stream>>>(src, trg, tnm, tns);
  transform_k<<<dim3(T_/32, C_/32, 2*B_), dim3(32,8), 0, stream>>>(src, trg,
      tnm, tns, inm, ins, NSt, NSc, NTt, NTc, TTr);
  zero_pad_k<<<16, blk, 0, stream>>>(x1p);
  zero_f32_k<<<192, blk, 0, stream>>>(colsum);    // whole contiguous zero block

  // QKV projections, both phases in one launch each.
  // z in [0,4): A = {NSc,NSt,NTc,NTt}[z], B = {wq_c,wq_t,wk_c,wk_t}[z]
  gemm_nt<0,4><<<dim3(C_/128, (B_*T_)/128, 4), blk, 0, stream>>>(NSc, WQb, QK4,
      C_, C_, C_, C_, BTC, (long long)C_*C_, BTC, 0, 1, 8, 1.f,
      nullptr, nullptr, nullptr, nullptr, nullptr, 0);
  // V^T[z] = wv[p] @ trg[b]^T -> [C,T]; z in [0,8): p=z/4, b=z%4
  gemm_nt<0,2><<<dim3(T_/64, C_/128, 8), blk, 0, stream>>>(WQb + (size_t)4*C_*C_, TTr, VT2,
      C_, C_, C_, T_, (long long)C_*C_, (long long)T_*C_, (long long)C_*T_, 0, 4, 4, 1.f,
      nullptr, nullptr, nullptr, nullptr, nullptr, 0);
  // P' = exp(Q @ K^T) bf16 + row sums l (no max-sub: logits ~ N(0,1))
  gemm_nt<4,4><<<dim3(T_/128, T_/128, 8), blk, 0, stream>>>(QK4, QK4 + 2*BTC, P2,
      C_, C_, C_, T_, (long long)T_*C_, (long long)T_*C_, (long long)S_*T_, 0, 1, 8, 1.f,
      nullptr, nullptr, nullptr, lrow, nullptr, S_);
  colsum_k<<<dim3(T_/256, S_/256, 8), blk, 0, stream>>>(P2, lrow, colsum);
  // PV with fused (1/l)-scaled sum_s / sum_s^2 epilogue (no output store)
  gemm_nt<3,4><<<dim3(C_/128, S_/128, 8), blk, 0, stream>>>(P2, VT2, nullptr,
      T_, T_, T_, 0, (long long)S_*T_, (long long)C_*T_, 0, C_, 1, 8, 1.f,
      lrow, nullptr, nullptr, msum, m2sum, S_);
  vv_fin_k<<<dim3(C_, 2*B_), blk, 0, stream>>>(colsum, VT2, msum, m2sum, meanc, stdc);

  // conv1 folded with adaptive-norm epilogues (TAN = phase 1, CAN = phase 0)
  weff_k<<<dim3(C_, B_), blk, 0, stream>>>(conv1w, conv1b,
      stdc + B_*C_, stdc, meanc + B_*C_, meanc, Weff, beff);
  gemm_nt<0,2><<<dim3(C_/64, T_/128, B_), blk, 0, stream>>>(NSc, Weff, x1p + C_,
      C_, C_, C_, C_, (long long)T_*C_, (long long)C_*C_, (long long)(T_+2)*C_, C_,
      1, 8, 1.f, nullptr, nullptr, beff, nullptr, nullptr, 0);
  // conv2 (k=3) as overlapping-row NT GEMM + BN+ReLU + fused row-stat sums
  gemm_nt<2,2><<<dim3(T_/64, C_/128, B_), blk, 0, stream>>>(W2r, x1p, y,
      3*C_, 3*C_, C_, T_, 0, (long long)(T_+2)*C_, (long long)C_*T_, 0,
      1, 8, 1.f, bnsc, bnsh, nullptr, ysum, y2sum, C_);

  sap_logit_k<<<dim3(S_/4, 2*B_), blk, 0, stream>>>(means, stds, msap_w, ssap_w,
      msap_b, ssap_b, sapl);
  softmax_row_k<<<2*B_, blk, 0, stream>>>(sapl, sapa);
  sap_wsum_k<<<dim3(C_/256, S_/256, 2*B_), blk, 0, stream>>>(means, stds, sapa, sapms);

  final_k<<<4096, blk, 0, stream>>>(y, ysum, y2sum, sapms, (float*)d_out);
}